// Round 12
// baseline (1153.818 us; speedup 1.0000x reference)
//
#include <hip/hip_runtime.h>
#include <hip/hip_bf16.h>

#define NCB 16
#define CS 256
#define HD 384
#define PD 2048
#define NROW 16384
#define NH 6144      // NCB*HD
#define LSR 5760     // (NCB-1)*HD  rows of linear_self
#define LSC 3840     // (NCB-1)*CS  cols of linear_self
#define SB_ROWS 32
#define SA_NBLK (NROW / SB_ROWS)   // 512
#define GNT (PD / 64)              // 32 K-tiles for gemm1

typedef __bf16 bf16x8 __attribute__((ext_vector_type(8)));
typedef float f32x4 __attribute__((ext_vector_type(4)));
typedef int int4v __attribute__((ext_vector_type(4)));

__device__ __forceinline__ unsigned short f2bf(float f) {
  unsigned u = __builtin_bit_cast(unsigned, f);
  u = (u + 0x7fffu + ((u >> 16) & 1u)) >> 16;
  return (unsigned short)u;
}
__device__ __forceinline__ float bf2f(unsigned short h) {
  unsigned u = ((unsigned)h) << 16;
  return __builtin_bit_cast(float, u);
}

__device__ __forceinline__ void gload16(void* lds, const void* g) {
  __builtin_amdgcn_global_load_lds(
      (const __attribute__((address_space(1))) unsigned int*)g,
      (__attribute__((address_space(3))) unsigned int*)lds, 16, 0, 0);
}

// ---------------- fp32 -> bf16 conversion ----------------
__global__ void k_f2b(const float* __restrict__ in, unsigned short* __restrict__ out, int n4) {
  for (int i = blockIdx.x * 256 + threadIdx.x; i < n4; i += gridDim.x * 256) {
    float4 v = ((const float4*)in)[i];
    ushort4 o;
    o.x = f2bf(v.x); o.y = f2bf(v.y); o.z = f2bf(v.z); o.w = f2bf(v.w);
    ((ushort4*)out)[i] = o;
  }
}

// ---------------- transpose linear_self (5760x3840 f32) -> T (3840x5760 bf16) ----------------
__global__ __launch_bounds__(256) void k_transpose(const float* __restrict__ LS,
                                                   unsigned short* __restrict__ T) {
  __shared__ float tile[32][33];
  int tx = threadIdx.x & 31, ty = threadIdx.x >> 5;
  int c0 = blockIdx.x * 32;  // col of LS = row of T
  int r0 = blockIdx.y * 32;  // row of LS = col of T
  for (int i = ty; i < 32; i += 8)
    tile[i][tx] = LS[(size_t)(r0 + i) * LSC + c0 + tx];
  __syncthreads();
  for (int i = ty; i < 32; i += 8)
    T[(size_t)(c0 + i) * LSR + r0 + tx] = f2bf(tile[tx][i]);
}

// ---------------- count valid[:,0] ----------------
__global__ void k_count(const int* __restrict__ ci, float* __restrict__ out) {
  int n = blockIdx.x * 256 + threadIdx.x;
  float v = (n < NROW && ci[(size_t)n * NCB] >= 0) ? 1.f : 0.f;
  #pragma unroll
  for (int m = 1; m < 64; m <<= 1) v += __shfl_xor(v, m);
  if ((threadIdx.x & 63) == 0) atomicAdd(out + 1, v);
}

// ---------------- GEMM1: 256x256 tile, BK=64 (2 k-halves), 8 waves, counted vmcnt ----------------
// r11 frozen: barrier#1 removed, counted vmcnt(8), XCD N-stripe swizzle.
__global__ __launch_bounds__(512, 2) void k_gemm1(
    const unsigned short* __restrict__ A,   // predictor bf16 [NROW][PD]
    const unsigned short* __restrict__ B,   // W1 bf16 [NH][PD]
    const float* __restrict__ b1,
    unsigned short* __restrict__ H) {       // out [NROW][NH]
  __shared__ int4 Al[2][2][1024];   // 64 KB
  __shared__ int4 Bl[2][2][1024];   // 64 KB

  const int tid = threadIdx.x;
  const int lane = tid & 63;
  const int w = tid >> 6;             // 0..7
  const int wr = w >> 2, wc = w & 3;  // wave grid 2(M) x 4(N)
  const int l15 = lane & 15, hi = lane >> 4;
  const int w64 = tid & ~63;

  // XCD swizzle: grid 1536 = 64 mt x 24 nt; each XCD owns 3 nt (3MB B -> L2)
  const int bid = blockIdx.x;
  const int xcd = bid & 7, p = bid >> 3;   // p in [0,192)
  const int nt = xcd * 3 + p % 3;
  const int mt = p / 3;
  const int tm = mt * 256, tn = nt * 256;

  f32x4 acc[8][4] = {};

  auto STAGE = [&](int buf, int t, int kh) {
    const int kb = t * 64 + kh * 32;
    #pragma unroll
    for (int g = 0; g < 2; ++g) {
      const int slot = g * 512 + tid;
      const int row = slot >> 2;                       // 0..255
      const int lc = (slot & 3) ^ ((row >> 1) & 3);    // inverse-swizzled source col
      gload16(&Al[buf][kh][g * 512 + w64], A + (size_t)(tm + row) * PD + kb + lc * 8);
      gload16(&Bl[buf][kh][g * 512 + w64], B + (size_t)(tn + row) * PD + kb + lc * 8);
    }
  };

  // prologue: t0.kh0, t0.kh1, t1.kh0 -> 12 loads; wait oldest 4 (t0.kh0)
  STAGE(0, 0, 0);
  STAGE(0, 0, 1);
  STAGE(1, 1, 0);
  asm volatile("s_waitcnt vmcnt(8)" ::: "memory");
  __builtin_amdgcn_s_barrier();

  for (int t = 0; t < GNT; ++t) {
    const int buf = t & 1;
    #pragma unroll
    for (int kh = 0; kh < 2; ++kh) {
      // frag reads (swizzled)
      int4 af[8], bfr[4];
      #pragma unroll
      for (int mi = 0; mi < 8; ++mi) {
        const int row = wr * 128 + mi * 16 + l15;
        const int pc = hi ^ ((row >> 1) & 3);
        af[mi] = Al[buf][kh][row * 4 + pc];
      }
      #pragma unroll
      for (int ni = 0; ni < 4; ++ni) {
        const int row = wc * 64 + ni * 16 + l15;
        const int pc = hi ^ ((row >> 1) & 3);
        bfr[ni] = Bl[buf][kh][row * 4 + pc];
      }
      // stage (regions race-safe, r7 audit)
      if (kh == 0) {
        if (t + 1 < GNT) STAGE(buf ^ 1, t + 1, 1);
      } else {
        if (t + 2 < GNT) STAGE(buf, t + 2, 0);
      }
      // (barrier #1 removed — cross-wave LDS/VALU vs MFMA overlap)
      __builtin_amdgcn_s_setprio(1);
      #pragma unroll
      for (int mi = 0; mi < 8; ++mi)
        #pragma unroll
        for (int ni = 0; ni < 4; ++ni)
          acc[mi][ni] = __builtin_amdgcn_mfma_f32_16x16x32_bf16(
              __builtin_bit_cast(bf16x8, af[mi]), __builtin_bit_cast(bf16x8, bfr[ni]),
              acc[mi][ni], 0, 0, 0);
      __builtin_amdgcn_s_setprio(0);
      // counted drains (audited): A-phase needs t.kh1; B-phase needs (t+1).kh0
      if (kh == 0) {
        if (t < GNT - 1) asm volatile("s_waitcnt vmcnt(8)" ::: "memory");
        else             asm volatile("s_waitcnt vmcnt(0)" ::: "memory");
      } else {
        if (t < GNT - 2)      asm volatile("s_waitcnt vmcnt(8)" ::: "memory");
        else if (t == GNT - 2) asm volatile("s_waitcnt vmcnt(4)" ::: "memory");
      }
      __builtin_amdgcn_s_barrier();
    }
  }

  // epilogue: bias + NT store
  #pragma unroll
  for (int ni = 0; ni < 4; ++ni) {
    const int col = tn + wc * 64 + ni * 16 + l15;
    const float bb = b1[col];
    #pragma unroll
    for (int mi = 0; mi < 8; ++mi)
      #pragma unroll
      for (int reg = 0; reg < 4; ++reg) {
        const int row = tm + wr * 128 + mi * 16 + hi * 4 + reg;
        __builtin_nontemporal_store(f2bf(acc[mi][ni][reg] + bb),
                                    H + (size_t)row * NH + col);
      }
  }
}

// ---------------- self-pred gather: 384-col stripes, XCD-paired T residency ----------------
// Stripe cb (0..15) covers cols [cb*384,(cb+1)*384): gather depth = cb (compile-time),
// T footprint = cb*192KB (rows < cb*256, one 384-col slice). Stripe x<8 -> cb=x,
// x>=8 -> cb=23-x pairs {k,15-k} on XCD k (bid%8=x%8): 2.9MB T per XCD -> L2-resident,
// and uniform gather work per XCD.
template <int CB>
__device__ __forceinline__ void sa_body(
    unsigned short* __restrict__ H, const unsigned short* __restrict__ T,
    const int (*idxs)[NCB], int row0, int chunk, int rsub, int col0, int o,
    float* __restrict__ sredS, float* __restrict__ sredQ) {
  float cs[8] = {0}, cq[8] = {0};
  for (int rr = 0; rr < SB_ROWS / 8; ++rr) {
    const int lrow = rr * 8 + rsub;
    const size_t ro = (size_t)(row0 + lrow) * NH;
    int4v hv = __builtin_nontemporal_load((const int4v*)(H + ro + col0));
    const unsigned short* hs = (const unsigned short*)&hv;
    float v[8];
    #pragma unroll
    for (int e = 0; e < 8; ++e) v[e] = bf2f(hs[e]);
    #pragma unroll
    for (int kc = 0; kc < CB; ++kc) {     // all kc < cb unmasked by triangle (o/HD == cb-1)
      int c = idxs[lrow][kc];
      float m = c >= 0 ? 1.f : 0.f;
      int cc = c < 0 ? 0 : (c > CS - 1 ? CS - 1 : c);
      int4v tv = *(const int4v*)(T + (size_t)(kc * CS + cc) * LSR + o);
      const unsigned short* ts = (const unsigned short*)&tv;
      #pragma unroll
      for (int e = 0; e < 8; ++e) v[e] = fmaf(m, bf2f(ts[e]), v[e]);
    }
    unsigned short os[8];
    #pragma unroll
    for (int e = 0; e < 8; ++e) {
      float x = fmaxf(v[e], 0.f);
      unsigned short hb = f2bf(x);
      os[e] = hb;
      float xr = bf2f(hb);
      cs[e] += xr;
      cq[e] += xr * xr;
    }
    __builtin_nontemporal_store(*(const int4v*)os, (int4v*)(H + ro + col0));
  }
  #pragma unroll
  for (int e = 0; e < 8; ++e) {
    sredS[rsub * 384 + chunk * 8 + e] = cs[e];
    sredQ[rsub * 384 + chunk * 8 + e] = cq[e];
  }
}

// grid dim3(16, SA_NBLK), block 384: 32 rows x one 384-col stripe per block
__global__ __launch_bounds__(384) void k_selfadd(
    unsigned short* __restrict__ H,        // [NROW][NH] bf16, in-place
    const unsigned short* __restrict__ T,  // [LSC][LSR] bf16 (linear_self^T)
    const int* __restrict__ ci,
    float* __restrict__ partials) {        // [2][SA_NBLK][NH]
  __shared__ int idxs[SB_ROWS][NCB];
  __shared__ float sredS[8 * 384], sredQ[8 * 384];
  const int tid = threadIdx.x;
  const int x = blockIdx.x;
  const int cb = (x < 8) ? x : 23 - x;     // XCD pairing {k, 15-k}
  const int row0 = blockIdx.y * SB_ROWS;
  for (int i = tid; i < SB_ROWS * NCB; i += 384)
    idxs[i >> 4][i & 15] = ci[(size_t)(row0 + (i >> 4)) * NCB + (i & 15)];
  __syncthreads();

  const int chunk = tid % 48;              // 8-col chunk within stripe
  const int rsub = tid / 48;               // 0..7
  const int col0 = cb * 384 + chunk * 8;
  const int o = col0 - HD < 0 ? 0 : col0 - HD;

  switch (cb) {
    case 0:  sa_body<0>(H, T, idxs, row0, chunk, rsub, col0, o, sredS, sredQ); break;
    case 1:  sa_body<1>(H, T, idxs, row0, chunk, rsub, col0, o, sredS, sredQ); break;
    case 2:  sa_body<2>(H, T, idxs, row0, chunk, rsub, col0, o, sredS, sredQ); break;
    case 3:  sa_body<3>(H, T, idxs, row0, chunk, rsub, col0, o, sredS, sredQ); break;
    case 4:  sa_body<4>(H, T, idxs, row0, chunk, rsub, col0, o, sredS, sredQ); break;
    case 5:  sa_body<5>(H, T, idxs, row0, chunk, rsub, col0, o, sredS, sredQ); break;
    case 6:  sa_body<6>(H, T, idxs, row0, chunk, rsub, col0, o, sredS, sredQ); break;
    case 7:  sa_body<7>(H, T, idxs, row0, chunk, rsub, col0, o, sredS, sredQ); break;
    case 8:  sa_body<8>(H, T, idxs, row0, chunk, rsub, col0, o, sredS, sredQ); break;
    case 9:  sa_body<9>(H, T, idxs, row0, chunk, rsub, col0, o, sredS, sredQ); break;
    case 10: sa_body<10>(H, T, idxs, row0, chunk, rsub, col0, o, sredS, sredQ); break;
    case 11: sa_body<11>(H, T, idxs, row0, chunk, rsub, col0, o, sredS, sredQ); break;
    case 12: sa_body<12>(H, T, idxs, row0, chunk, rsub, col0, o, sredS, sredQ); break;
    case 13: sa_body<13>(H, T, idxs, row0, chunk, rsub, col0, o, sredS, sredQ); break;
    case 14: sa_body<14>(H, T, idxs, row0, chunk, rsub, col0, o, sredS, sredQ); break;
    default: sa_body<15>(H, T, idxs, row0, chunk, rsub, col0, o, sredS, sredQ); break;
  }
  __syncthreads();

  const int j = tid;                        // 0..383: one stripe col each
  float s = 0.f, q = 0.f;
  #pragma unroll
  for (int r = 0; r < 8; ++r) {
    s += sredS[r * 384 + j];
    q += sredQ[r * 384 + j];
  }
  partials[(size_t)blockIdx.y * NH + cb * 384 + j] = s;
  partials[(size_t)(SA_NBLK + blockIdx.y) * NH + cb * 384 + j] = q;
}

// ---------------- reduce partials -> colsum/colsq ----------------
// grid dim3(NH/256, 8)
__global__ void k_red(const float* __restrict__ partials,
                      float* __restrict__ colsum, float* __restrict__ colsq) {
  int j = blockIdx.x * 256 + threadIdx.x;
  const float* Ps = partials;
  const float* Pq = partials + (size_t)SA_NBLK * NH;
  float s = 0.f, q = 0.f;
  const int b0 = blockIdx.y * (SA_NBLK / 8), b1 = b0 + SA_NBLK / 8;
  for (int by = b0; by < b1; ++by) {
    s += Ps[(size_t)by * NH + j];
    q += Pq[(size_t)by * NH + j];
  }
  atomicAdd(colsum + j, s);
  atomicAdd(colsq + j, q);
}

// ---------------- BN params ----------------
__global__ void k_bn(const float* __restrict__ colsum, const float* __restrict__ colsq,
                     const float* __restrict__ gamma, const float* __restrict__ beta,
                     float* __restrict__ scale, float* __restrict__ shift) {
  int j = blockIdx.x * 256 + threadIdx.x;
  if (j >= NH) return;
  float mean = colsum[j] * (1.f / NROW);
  float var = colsq[j] * (1.f / NROW) - mean * mean;
  var = fmaxf(var, 0.f);
  float rs = rsqrtf(var + 1e-5f);
  float g = gamma[j] * rs;
  scale[j] = g;
  shift[j] = beta[j] - mean * g;
}

// ---------------- fold BN into linear2/bias2 ----------------
__global__ __launch_bounds__(128) void k_fold(
    const float* __restrict__ L2, const float* __restrict__ bias2,
    const float* __restrict__ scale, const float* __restrict__ shift,
    unsigned short* __restrict__ L2b, float* __restrict__ bias2p) {
  __shared__ float red[2];
  int kc = blockIdx.x;        // k*256 + c
  int k = kc >> 8;
  size_t off = (size_t)kc * HD;
  float a = 0.f;
  for (int h = threadIdx.x; h < HD; h += 128) {
    float wv = L2[off + h];
    int jh = k * HD + h;
    L2b[off + h] = f2bf(wv * scale[jh]);
    a += wv * shift[jh];
  }
  #pragma unroll
  for (int m = 1; m < 64; m <<= 1) a += __shfl_xor(a, m);
  if ((threadIdx.x & 63) == 0) red[threadIdx.x >> 6] = a;
  __syncthreads();
  if (threadIdx.x == 0) bias2p[kc] = bias2[kc] + red[0] + red[1];
}

// ---------------- pass C: logits GEMM + log-softmax + target gather ----------------
// grid dim3(256,16); XCD swizzle (2 codebooks/XCD); dbuf staging; single-pass
// softmax (no max subtraction — logits bounded ~|10|, exp safe in f32).
__global__ __launch_bounds__(256, 2) void k_passc(
    const unsigned short* __restrict__ H,     // [NROW][NH] bf16
    const unsigned short* __restrict__ L2b,   // [NCB][CS][HD] bf16 (BN-folded)
    const float* __restrict__ bias2p,         // [NCB][CS]
    const int* __restrict__ ci,
    float* __restrict__ out) {
  __shared__ char smem[64 * 260 * 4];  // 66560B; staging dbuf (40KB) aliased under lg
  __shared__ float red[4];
  float* lg = (float*)smem;            // [64][260]

  const int tid = threadIdx.x, lane = tid & 63, w = tid >> 6;
  const int bidf = blockIdx.y * gridDim.x + blockIdx.x;  // 0..4095
  const int xcd = bidf & 7, p = bidf >> 3;               // p in [0,512)
  const int k = xcd * 2 + (p & 1);
  const int tm = (p >> 1) * 64;
  const int r = lane & 15, kg = lane >> 4;

  auto Asb = [&](int buf) { return (int4*)(smem + buf * 20480); };          // 4KB
  auto Bsb = [&](int buf) { return (int4*)(smem + buf * 20480 + 4096); };   // 16KB

  const int s0r = (w * 64 + lane) & 63, s0g = (w * 64 + lane) >> 6;
  auto STAGE = [&](int buf, int kk) {
    const int k0 = kk * 32;
    gload16(Asb(buf) + w * 64, H + (size_t)(tm + s0r) * NH + k * HD + k0 + s0g * 8);
    #pragma unroll
    for (int i = 0; i < 4; ++i) {
      int s = i * 256 + w * 64 + lane;
      int srow = s & 255, skg = s >> 8;
      gload16(Bsb(buf) + i * 256 + w * 64,
              L2b + (size_t)(k * CS + srow) * HD + k0 + skg * 8);
    }
  };

  f32x4 acc[4][4] = {};
  int buf = 0;
  STAGE(0, 0);
  asm volatile("s_waitcnt vmcnt(0)" ::: "memory");
  __syncthreads();

  for (int kk = 0; kk < HD / 32; ++kk) {  // 12 steps
    if (kk + 1 < HD / 32) STAGE(buf ^ 1, kk + 1);
    int4 af[4], bfr[4];
    #pragma unroll
    for (int mi = 0; mi < 4; ++mi) af[mi] = Asb(buf)[kg * 64 + mi * 16 + r];
    #pragma unroll
    for (int ni = 0; ni < 4; ++ni) bfr[ni] = Bsb(buf)[kg * 256 + w * 64 + ni * 16 + r];
    #pragma unroll
    for (int mi = 0; mi < 4; ++mi)
      #pragma unroll
      for (int ni = 0; ni < 4; ++ni)
        acc[mi][ni] = __builtin_amdgcn_mfma_f32_16x16x32_bf16(
            __builtin_bit_cast(bf16x8, af[mi]), __builtin_bit_cast(bf16x8, bfr[ni]),
            acc[mi][ni], 0, 0, 0);
    __syncthreads();
    buf ^= 1;
  }

  const int lr0 = (lane >> 4) * 4;
  #pragma unroll
  for (int mi = 0; mi < 4; ++mi)
    #pragma unroll
    for (int ni = 0; ni < 4; ++ni) {
      int col = w * 64 + ni * 16 + r;
      float bb = bias2p[k * CS + col];
      #pragma unroll
      for (int reg = 0; reg < 4; ++reg) {
        int row = mi * 16 + lr0 + reg;
        lg[row * 260 + col] = acc[mi][ni][reg] + bb;
      }
    }
  __syncthreads();

  int row = tid >> 2, part = tid & 3;
  const float4* rp = (const float4*)(lg + row * 260 + part * 64);
  float s = 0.f;
  #pragma unroll
  for (int i = 0; i < 16; ++i) {
    float4 v = rp[i];
    s += __expf(v.x) + __expf(v.y) + __expf(v.z) + __expf(v.w);
  }
  s += __shfl_xor(s, 1);
  s += __shfl_xor(s, 2);
  float contrib = 0.f;
  if (part == 0) {
    float lse = __logf(s);
    int c = ci[(size_t)(tm + row) * NCB + k];
    if (c >= 0) {
      c = c < CS ? c : CS - 1;
      contrib = lg[row * 260 + c] - lse;
    }
  }
  #pragma unroll
  for (int msk = 1; msk < 64; msk <<= 1) contrib += __shfl_xor(contrib, msk);
  if (lane == 0) red[w] = contrib;
  __syncthreads();
  if (tid == 0) atomicAdd(out, red[0] + red[1] + red[2] + red[3]);
}

extern "C" void kernel_launch(void* const* d_in, const int* in_sizes, int n_in,
                              void* d_out, int out_size, void* d_ws, size_t ws_size,
                              hipStream_t stream) {
  const float* predictor = (const float*)d_in[0];
  const int* cbidx       = (const int*)d_in[1];
  const float* W1        = (const float*)d_in[2];
  const float* b1        = (const float*)d_in[3];
  const float* lself     = (const float*)d_in[4];
  const float* gamma     = (const float*)d_in[5];
  const float* beta      = (const float*)d_in[6];
  const float* L2        = (const float*)d_in[7];
  const float* bias2     = (const float*)d_in[8];
  float* out = (float*)d_out;

  char* ws = (char*)d_ws;
  size_t off = 0;
  auto alloc = [&](size_t bytes) {
    char* p = ws + off;
    off += (bytes + 255) & ~(size_t)255;
    return p;
  };
  unsigned short* predB  = (unsigned short*)alloc((size_t)NROW * PD * 2);
  unsigned short* W1B    = (unsigned short*)alloc((size_t)NH * PD * 2);
  unsigned short* T      = (unsigned short*)alloc((size_t)LSC * LSR * 2);
  unsigned short* Hb     = (unsigned short*)alloc((size_t)NROW * NH * 2);
  unsigned short* L2b    = (unsigned short*)alloc((size_t)NCB * CS * HD * 2);
  float* partials = (float*)alloc((size_t)2 * SA_NBLK * NH * 4);
  float* colsum = (float*)alloc(NH * 4);
  float* colsq  = (float*)alloc(NH * 4);
  float* scale  = (float*)alloc(NH * 4);
  float* shift  = (float*)alloc(NH * 4);
  float* bias2p = (float*)alloc(NCB * CS * 4);

  hipMemsetAsync(d_out, 0, 2 * sizeof(float), stream);
  hipMemsetAsync(colsum, 0, NH * 4, stream);
  hipMemsetAsync(colsq, 0, NH * 4, stream);

  k_f2b<<<2048, 256, 0, stream>>>(predictor, predB, NROW * PD / 4);
  k_f2b<<<2048, 256, 0, stream>>>(W1, W1B, NH * PD / 4);
  k_transpose<<<dim3(LSC / 32, LSR / 32), 256, 0, stream>>>(lself, T);
  k_count<<<NROW / 256, 256, 0, stream>>>(cbidx, out);
  k_gemm1<<<(NROW / 256) * (NH / 256), 512, 0, stream>>>(predB, W1B, b1, Hb);
  k_selfadd<<<dim3(16, SA_NBLK), 384, 0, stream>>>(Hb, T, cbidx, partials);
  k_red<<<dim3(NH / 256, 8), 256, 0, stream>>>(partials, colsum, colsq);
  k_bn<<<NH / 256, 256, 0, stream>>>(colsum, colsq, gamma, beta, scale, shift);
  k_fold<<<NCB * CS, 128, 0, stream>>>(L2, bias2, scale, shift, L2b, bias2p);
  k_passc<<<dim3(NROW / 64, NCB), 256, 0, stream>>>(Hb, L2b, bias2p, cbidx, out);
}

// Round 13
// 1097.193 us; speedup vs baseline: 1.0516x; 1.0516x over previous
//
#include <hip/hip_runtime.h>
#include <hip/hip_bf16.h>

#define NCB 16
#define CS 256
#define HD 384
#define PD 2048
#define NROW 16384
#define NH 6144      // NCB*HD
#define LSR 5760     // (NCB-1)*HD  rows of linear_self
#define LSC 3840     // (NCB-1)*CS  cols of linear_self
#define SA_ROWS 32
#define SA_NBLK (NROW / SA_ROWS)   // 512
#define GNT (PD / 64)              // 32 K-tiles for gemm1

typedef __bf16 bf16x8 __attribute__((ext_vector_type(8)));
typedef float f32x4 __attribute__((ext_vector_type(4)));
typedef int int4v __attribute__((ext_vector_type(4)));

__device__ __forceinline__ unsigned short f2bf(float f) {
  unsigned u = __builtin_bit_cast(unsigned, f);
  u = (u + 0x7fffu + ((u >> 16) & 1u)) >> 16;
  return (unsigned short)u;
}
__device__ __forceinline__ float bf2f(unsigned short h) {
  unsigned u = ((unsigned)h) << 16;
  return __builtin_bit_cast(float, u);
}

__device__ __forceinline__ void gload16(void* lds, const void* g) {
  __builtin_amdgcn_global_load_lds(
      (const __attribute__((address_space(1))) unsigned int*)g,
      (__attribute__((address_space(3))) unsigned int*)lds, 16, 0, 0);
}

// ---------------- fp32 -> bf16 conversion ----------------
__global__ void k_f2b(const float* __restrict__ in, unsigned short* __restrict__ out, int n4) {
  for (int i = blockIdx.x * 256 + threadIdx.x; i < n4; i += gridDim.x * 256) {
    float4 v = ((const float4*)in)[i];
    ushort4 o;
    o.x = f2bf(v.x); o.y = f2bf(v.y); o.z = f2bf(v.z); o.w = f2bf(v.w);
    ((ushort4*)out)[i] = o;
  }
}

// ---------------- transpose linear_self (5760x3840 f32) -> T (3840x5760 bf16) ----------------
__global__ __launch_bounds__(256) void k_transpose(const float* __restrict__ LS,
                                                   unsigned short* __restrict__ T) {
  __shared__ float tile[32][33];
  int tx = threadIdx.x & 31, ty = threadIdx.x >> 5;
  int c0 = blockIdx.x * 32;  // col of LS = row of T
  int r0 = blockIdx.y * 32;  // row of LS = col of T
  for (int i = ty; i < 32; i += 8)
    tile[i][tx] = LS[(size_t)(r0 + i) * LSC + c0 + tx];
  __syncthreads();
  for (int i = ty; i < 32; i += 8)
    T[(size_t)(c0 + i) * LSR + r0 + tx] = f2bf(tile[tx][i]);
}

// ---------------- count valid[:,0] ----------------
__global__ void k_count(const int* __restrict__ ci, float* __restrict__ out) {
  int n = blockIdx.x * 256 + threadIdx.x;
  float v = (n < NROW && ci[(size_t)n * NCB] >= 0) ? 1.f : 0.f;
  #pragma unroll
  for (int m = 1; m < 64; m <<= 1) v += __shfl_xor(v, m);
  if ((threadIdx.x & 63) == 0) atomicAdd(out + 1, v);
}

// ---------------- GEMM1: 256x256 tile, BK=64 (2 k-halves), 8 waves, counted vmcnt ----------------
// r11 frozen: barrier#1 removed, counted vmcnt(8), XCD N-stripe swizzle.
__global__ __launch_bounds__(512, 2) void k_gemm1(
    const unsigned short* __restrict__ A,   // predictor bf16 [NROW][PD]
    const unsigned short* __restrict__ B,   // W1 bf16 [NH][PD]
    const float* __restrict__ b1,
    unsigned short* __restrict__ H) {       // out [NROW][NH]
  __shared__ int4 Al[2][2][1024];   // 64 KB
  __shared__ int4 Bl[2][2][1024];   // 64 KB

  const int tid = threadIdx.x;
  const int lane = tid & 63;
  const int w = tid >> 6;             // 0..7
  const int wr = w >> 2, wc = w & 3;  // wave grid 2(M) x 4(N)
  const int l15 = lane & 15, hi = lane >> 4;
  const int w64 = tid & ~63;

  // XCD swizzle: grid 1536 = 64 mt x 24 nt; each XCD owns 3 nt (3MB B -> L2)
  const int bid = blockIdx.x;
  const int xcd = bid & 7, p = bid >> 3;   // p in [0,192)
  const int nt = xcd * 3 + p % 3;
  const int mt = p / 3;
  const int tm = mt * 256, tn = nt * 256;

  f32x4 acc[8][4] = {};

  auto STAGE = [&](int buf, int t, int kh) {
    const int kb = t * 64 + kh * 32;
    #pragma unroll
    for (int g = 0; g < 2; ++g) {
      const int slot = g * 512 + tid;
      const int row = slot >> 2;                       // 0..255
      const int lc = (slot & 3) ^ ((row >> 1) & 3);    // inverse-swizzled source col
      gload16(&Al[buf][kh][g * 512 + w64], A + (size_t)(tm + row) * PD + kb + lc * 8);
      gload16(&Bl[buf][kh][g * 512 + w64], B + (size_t)(tn + row) * PD + kb + lc * 8);
    }
  };

  // prologue: t0.kh0, t0.kh1, t1.kh0 -> 12 loads; wait oldest 4 (t0.kh0)
  STAGE(0, 0, 0);
  STAGE(0, 0, 1);
  STAGE(1, 1, 0);
  asm volatile("s_waitcnt vmcnt(8)" ::: "memory");
  __builtin_amdgcn_s_barrier();

  for (int t = 0; t < GNT; ++t) {
    const int buf = t & 1;
    #pragma unroll
    for (int kh = 0; kh < 2; ++kh) {
      // frag reads (swizzled)
      int4 af[8], bfr[4];
      #pragma unroll
      for (int mi = 0; mi < 8; ++mi) {
        const int row = wr * 128 + mi * 16 + l15;
        const int pc = hi ^ ((row >> 1) & 3);
        af[mi] = Al[buf][kh][row * 4 + pc];
      }
      #pragma unroll
      for (int ni = 0; ni < 4; ++ni) {
        const int row = wc * 64 + ni * 16 + l15;
        const int pc = hi ^ ((row >> 1) & 3);
        bfr[ni] = Bl[buf][kh][row * 4 + pc];
      }
      // stage (regions race-safe, r7 audit)
      if (kh == 0) {
        if (t + 1 < GNT) STAGE(buf ^ 1, t + 1, 1);
      } else {
        if (t + 2 < GNT) STAGE(buf, t + 2, 0);
      }
      // (barrier #1 removed — cross-wave LDS/VALU vs MFMA overlap)
      __builtin_amdgcn_s_setprio(1);
      #pragma unroll
      for (int mi = 0; mi < 8; ++mi)
        #pragma unroll
        for (int ni = 0; ni < 4; ++ni)
          acc[mi][ni] = __builtin_amdgcn_mfma_f32_16x16x32_bf16(
              __builtin_bit_cast(bf16x8, af[mi]), __builtin_bit_cast(bf16x8, bfr[ni]),
              acc[mi][ni], 0, 0, 0);
      __builtin_amdgcn_s_setprio(0);
      // counted drains (audited): A-phase needs t.kh1; B-phase needs (t+1).kh0
      if (kh == 0) {
        if (t < GNT - 1) asm volatile("s_waitcnt vmcnt(8)" ::: "memory");
        else             asm volatile("s_waitcnt vmcnt(0)" ::: "memory");
      } else {
        if (t < GNT - 2)      asm volatile("s_waitcnt vmcnt(8)" ::: "memory");
        else if (t == GNT - 2) asm volatile("s_waitcnt vmcnt(4)" ::: "memory");
      }
      __builtin_amdgcn_s_barrier();
    }
  }

  // epilogue: bias + NT store
  #pragma unroll
  for (int ni = 0; ni < 4; ++ni) {
    const int col = tn + wc * 64 + ni * 16 + l15;
    const float bb = b1[col];
    #pragma unroll
    for (int mi = 0; mi < 8; ++mi)
      #pragma unroll
      for (int reg = 0; reg < 4; ++reg) {
        const int row = tm + wr * 128 + mi * 16 + hi * 4 + reg;
        __builtin_nontemporal_store(f2bf(acc[mi][ni][reg] + bb),
                                    H + (size_t)row * NH + col);
      }
  }
}

// ---------------- self-pred gather: branch-free unrolled (r11 verbatim) ----------------
template <int KM>
__device__ __forceinline__ void gather_chunk(
    const unsigned short* __restrict__ T, const int* idxrow,
    int oo, int bbv, float v[8]) {
  #pragma unroll
  for (int kc = 0; kc < KM; ++kc) {
    int c = idxrow[kc];
    float m = (c >= 0 && kc <= bbv) ? 1.f : 0.f;
    int cc = c < 0 ? 0 : (c >= CS ? CS - 1 : c);
    int4v tv = *(const int4v*)(T + (size_t)(kc * CS + cc) * LSR + oo);
    const unsigned short* ts = (const unsigned short*)&tv;
    #pragma unroll
    for (int e = 0; e < 8; ++e) v[e] = fmaf(m, bf2f(ts[e]), v[e]);
  }
}

// grid = dim3(3, SA_NBLK): x = 2048-col stripe (compile-time gather depth),
// y = 32-row block. 1536 blocks -> 6/CU. One 8-col chunk per thread per row.
__global__ __launch_bounds__(256) void k_selfadd(
    unsigned short* __restrict__ H,        // [NROW][NH] bf16, in-place
    const unsigned short* __restrict__ T,  // [LSC][LSR] bf16 (linear_self^T)
    const int* __restrict__ ci,
    float* __restrict__ partials) {        // [2][SA_NBLK][NH]
  __shared__ int idxs[SA_ROWS][NCB];
  const int tid = threadIdx.x;
  const int row0 = blockIdx.y * SA_ROWS;
  const int sx = blockIdx.x;               // 0..2, block-uniform
  for (int i = tid; i < SA_ROWS * NCB; i += 256)
    idxs[i >> 4][i & 15] = ci[(size_t)(row0 + (i >> 4)) * NCB + (i & 15)];
  __syncthreads();

  const int col0 = sx * 2048 + tid * 8;
  const int o = col0 - HD;
  const int oo = o < 0 ? 0 : o;
  const int bb = o < 0 ? -1 : o / HD;

  float cs[8] = {0}, cq[8] = {0};

  for (int rr = 0; rr < SA_ROWS; ++rr) {
    const size_t ro = (size_t)(row0 + rr) * NH;
    int4v hv = __builtin_nontemporal_load((const int4v*)(H + ro + col0));
    const unsigned short* hs = (const unsigned short*)&hv;
    float v[8];
    #pragma unroll
    for (int e = 0; e < 8; ++e) v[e] = bf2f(hs[e]);
    switch (sx) {  // block-uniform branch, compile-time gather depth
      case 0: gather_chunk<5>(T, idxs[rr], oo, bb, v); break;
      case 1: gather_chunk<10>(T, idxs[rr], oo, bb, v); break;
      default: gather_chunk<15>(T, idxs[rr], oo, bb, v); break;
    }
    unsigned short os[8];
    #pragma unroll
    for (int e = 0; e < 8; ++e) {
      float x = fmaxf(v[e], 0.f);
      unsigned short hb = f2bf(x);
      os[e] = hb;
      float xr = bf2f(hb);
      cs[e] += xr;
      cq[e] += xr * xr;
    }
    // NT store: keep T resident in L2/L3; passc re-fetches H from HBM anyway
    __builtin_nontemporal_store(*(const int4v*)os, (int4v*)(H + ro + col0));
  }

  float* Ps = partials + (size_t)blockIdx.y * NH + col0;
  float* Pq = partials + (size_t)(SA_NBLK + blockIdx.y) * NH + col0;
  float4 a = {cs[0], cs[1], cs[2], cs[3]};
  float4 b4 = {cs[4], cs[5], cs[6], cs[7]};
  *(float4*)Ps = a; *(float4*)(Ps + 4) = b4;
  float4 c4 = {cq[0], cq[1], cq[2], cq[3]};
  float4 d4 = {cq[4], cq[5], cq[6], cq[7]};
  *(float4*)Pq = c4; *(float4*)(Pq + 4) = d4;
}

// ---------------- reduce partials -> colsum/colsq ----------------
// grid dim3(NH/256, 8)
__global__ void k_red(const float* __restrict__ partials,
                      float* __restrict__ colsum, float* __restrict__ colsq) {
  int j = blockIdx.x * 256 + threadIdx.x;
  const float* Ps = partials;
  const float* Pq = partials + (size_t)SA_NBLK * NH;
  float s = 0.f, q = 0.f;
  const int b0 = blockIdx.y * (SA_NBLK / 8), b1 = b0 + SA_NBLK / 8;
  for (int by = b0; by < b1; ++by) {
    s += Ps[(size_t)by * NH + j];
    q += Pq[(size_t)by * NH + j];
  }
  atomicAdd(colsum + j, s);
  atomicAdd(colsq + j, q);
}

// ---------------- BN params ----------------
__global__ void k_bn(const float* __restrict__ colsum, const float* __restrict__ colsq,
                     const float* __restrict__ gamma, const float* __restrict__ beta,
                     float* __restrict__ scale, float* __restrict__ shift) {
  int j = blockIdx.x * 256 + threadIdx.x;
  if (j >= NH) return;
  float mean = colsum[j] * (1.f / NROW);
  float var = colsq[j] * (1.f / NROW) - mean * mean;
  var = fmaxf(var, 0.f);
  float rs = rsqrtf(var + 1e-5f);
  float g = gamma[j] * rs;
  scale[j] = g;
  shift[j] = beta[j] - mean * g;
}

// ---------------- fold BN into linear2/bias2 ----------------
__global__ __launch_bounds__(128) void k_fold(
    const float* __restrict__ L2, const float* __restrict__ bias2,
    const float* __restrict__ scale, const float* __restrict__ shift,
    unsigned short* __restrict__ L2b, float* __restrict__ bias2p) {
  __shared__ float red[2];
  int kc = blockIdx.x;        // k*256 + c
  int k = kc >> 8;
  size_t off = (size_t)kc * HD;
  float a = 0.f;
  for (int h = threadIdx.x; h < HD; h += 128) {
    float wv = L2[off + h];
    int jh = k * HD + h;
    L2b[off + h] = f2bf(wv * scale[jh]);
    a += wv * shift[jh];
  }
  #pragma unroll
  for (int m = 1; m < 64; m <<= 1) a += __shfl_xor(a, m);
  if ((threadIdx.x & 63) == 0) red[threadIdx.x >> 6] = a;
  __syncthreads();
  if (threadIdx.x == 0) bias2p[kc] = bias2[kc] + red[0] + red[1];
}

// ---------------- pass C: logits GEMM + log-softmax + target gather ----------------
// grid dim3(256,16); XCD swizzle (2 codebooks/XCD -> L2b panels L2-resident).
// 3-region LDS rotation with counted vmcnt(5): stage 2 phases ahead, raw
// s_barrier per phase (no full drain). Region written at phase P was last
// read at P-1; readers consumed data (MFMA lgkm waits) before the P-1 barrier.
__global__ __launch_bounds__(256, 2) void k_passc(
    const unsigned short* __restrict__ H,     // [NROW][NH] bf16
    const unsigned short* __restrict__ L2b,   // [NCB][CS][HD] bf16 (BN-folded)
    const float* __restrict__ bias2p,         // [NCB][CS]
    const int* __restrict__ ci,
    float* __restrict__ out) {
  __shared__ char smem[64 * 260 * 4];  // 66560B; 3x20480 staging aliased under lg
  __shared__ float red[4];
  float* lg = (float*)smem;            // [64][260]

  const int tid = threadIdx.x, lane = tid & 63, w = tid >> 6;
  const int bidf = blockIdx.y * gridDim.x + blockIdx.x;  // 0..4095
  const int xcd = bidf & 7, p = bidf >> 3;               // p in [0,512)
  const int k = xcd * 2 + (p & 1);
  const int tm = (p >> 1) * 64;
  const int r = lane & 15, kg = lane >> 4;

  auto Asb = [&](int r3) { return (int4*)(smem + r3 * 20480); };          // 4KB
  auto Bsb = [&](int r3) { return (int4*)(smem + r3 * 20480 + 4096); };   // 16KB

  const int s0r = (w * 64 + lane) & 63, s0g = (w * 64 + lane) >> 6;
  auto STAGE = [&](int r3, int kk) {
    const int k0 = kk * 32;
    gload16(Asb(r3) + w * 64, H + (size_t)(tm + s0r) * NH + k * HD + k0 + s0g * 8);
    #pragma unroll
    for (int i = 0; i < 4; ++i) {
      int s = i * 256 + w * 64 + lane;
      int srow = s & 255, skg = s >> 8;
      gload16(Bsb(r3) + i * 256 + w * 64,
              L2b + (size_t)(k * CS + srow) * HD + k0 + skg * 8);
    }
  };

  f32x4 acc[4][4] = {};
  STAGE(0, 0);
  STAGE(1, 1);
  asm volatile("s_waitcnt vmcnt(5)" ::: "memory");   // region 0 landed
  __builtin_amdgcn_s_barrier();

  for (int kk = 0; kk < HD / 32; ++kk) {  // 12 phases
    const int r3 = kk % 3;
    int4 af[4], bfr[4];
    #pragma unroll
    for (int mi = 0; mi < 4; ++mi) af[mi] = Asb(r3)[kg * 64 + mi * 16 + r];
    #pragma unroll
    for (int ni = 0; ni < 4; ++ni) bfr[ni] = Bsb(r3)[kg * 256 + w * 64 + ni * 16 + r];
    if (kk + 2 < HD / 32) STAGE((kk + 2) % 3, kk + 2);   // overwrites region read at kk-1
    __builtin_amdgcn_s_setprio(1);
    #pragma unroll
    for (int mi = 0; mi < 4; ++mi)
      #pragma unroll
      for (int ni = 0; ni < 4; ++ni)
        acc[mi][ni] = __builtin_amdgcn_mfma_f32_16x16x32_bf16(
            __builtin_bit_cast(bf16x8, af[mi]), __builtin_bit_cast(bf16x8, bfr[ni]),
            acc[mi][ni], 0, 0, 0);
    __builtin_amdgcn_s_setprio(0);
    if (kk + 1 < HD / 32) {
      if (kk + 2 < HD / 32) asm volatile("s_waitcnt vmcnt(5)" ::: "memory");
      else                  asm volatile("s_waitcnt vmcnt(0)" ::: "memory");
    }
    __builtin_amdgcn_s_barrier();
  }

  const int lr0 = (lane >> 4) * 4;
  #pragma unroll
  for (int mi = 0; mi < 4; ++mi)
    #pragma unroll
    for (int ni = 0; ni < 4; ++ni) {
      int col = w * 64 + ni * 16 + r;
      float bb = bias2p[k * CS + col];
      #pragma unroll
      for (int reg = 0; reg < 4; ++reg) {
        int row = mi * 16 + lr0 + reg;
        lg[row * 260 + col] = acc[mi][ni][reg] + bb;
      }
    }
  __syncthreads();

  int row = tid >> 2, part = tid & 3;
  const float4* rp = (const float4*)(lg + row * 260 + part * 64);
  float s = 0.f;
  #pragma unroll
  for (int i = 0; i < 16; ++i) {
    float4 v = rp[i];
    s += __expf(v.x) + __expf(v.y) + __expf(v.z) + __expf(v.w);
  }
  s += __shfl_xor(s, 1);
  s += __shfl_xor(s, 2);
  float contrib = 0.f;
  if (part == 0) {
    float lse = __logf(s);
    int c = ci[(size_t)(tm + row) * NCB + k];
    if (c >= 0) {
      c = c < CS ? c : CS - 1;
      contrib = lg[row * 260 + c] - lse;
    }
  }
  #pragma unroll
  for (int msk = 1; msk < 64; msk <<= 1) contrib += __shfl_xor(contrib, msk);
  if (lane == 0) red[w] = contrib;
  __syncthreads();
  if (tid == 0) atomicAdd(out, red[0] + red[1] + red[2] + red[3]);
}

extern "C" void kernel_launch(void* const* d_in, const int* in_sizes, int n_in,
                              void* d_out, int out_size, void* d_ws, size_t ws_size,
                              hipStream_t stream) {
  const float* predictor = (const float*)d_in[0];
  const int* cbidx       = (const int*)d_in[1];
  const float* W1        = (const float*)d_in[2];
  const float* b1        = (const float*)d_in[3];
  const float* lself     = (const float*)d_in[4];
  const float* gamma     = (const float*)d_in[5];
  const float* beta      = (const float*)d_in[6];
  const float* L2        = (const float*)d_in[7];
  const float* bias2     = (const float*)d_in[8];
  float* out = (float*)d_out;

  char* ws = (char*)d_ws;
  size_t off = 0;
  auto alloc = [&](size_t bytes) {
    char* p = ws + off;
    off += (bytes + 255) & ~(size_t)255;
    return p;
  };
  unsigned short* predB  = (unsigned short*)alloc((size_t)NROW * PD * 2);
  unsigned short* W1B    = (unsigned short*)alloc((size_t)NH * PD * 2);
  unsigned short* T      = (unsigned short*)alloc((size_t)LSC * LSR * 2);
  unsigned short* Hb     = (unsigned short*)alloc((size_t)NROW * NH * 2);
  unsigned short* L2b    = (unsigned short*)alloc((size_t)NCB * CS * HD * 2);
  float* partials = (float*)alloc((size_t)2 * SA_NBLK * NH * 4);
  float* colsum = (float*)alloc(NH * 4);
  float* colsq  = (float*)alloc(NH * 4);
  float* scale  = (float*)alloc(NH * 4);
  float* shift  = (float*)alloc(NH * 4);
  float* bias2p = (float*)alloc(NCB * CS * 4);

  hipMemsetAsync(d_out, 0, 2 * sizeof(float), stream);
  hipMemsetAsync(colsum, 0, NH * 4, stream);
  hipMemsetAsync(colsq, 0, NH * 4, stream);

  k_f2b<<<2048, 256, 0, stream>>>(predictor, predB, NROW * PD / 4);
  k_f2b<<<2048, 256, 0, stream>>>(W1, W1B, NH * PD / 4);
  k_transpose<<<dim3(LSC / 32, LSR / 32), 256, 0, stream>>>(lself, T);
  k_count<<<NROW / 256, 256, 0, stream>>>(cbidx, out);
  k_gemm1<<<(NROW / 256) * (NH / 256), 512, 0, stream>>>(predB, W1B, b1, Hb);
  k_selfadd<<<dim3(3, SA_NBLK), 256, 0, stream>>>(Hb, T, cbidx, partials);
  k_red<<<dim3(NH / 256, 8), 256, 0, stream>>>(partials, colsum, colsq);
  k_bn<<<NH / 256, 256, 0, stream>>>(colsum, colsq, gamma, beta, scale, shift);
  k_fold<<<NCB * CS, 128, 0, stream>>>(L2, bias2, scale, shift, L2b, bias2p);
  k_passc<<<dim3(NROW / 64, NCB), 256, 0, stream>>>(Hb, L2b, bias2p, cbidx, out);
}

// Round 14
// 953.709 us; speedup vs baseline: 1.2098x; 1.1504x over previous
//
#include <hip/hip_runtime.h>
#include <hip/hip_bf16.h>

#define NCB 16
#define CS 256
#define HD 384
#define PD 2048
#define NROW 16384
#define NH 6144      // NCB*HD
#define LSR 5760     // (NCB-1)*HD  rows of linear_self
#define LSC 3840     // (NCB-1)*CS  cols of linear_self
#define SA_ROWS 32
#define SA_NBLK (NROW / SA_ROWS)   // 512
#define GNT (PD / 64)              // 32 K-tiles for gemm1

typedef __bf16 bf16x8 __attribute__((ext_vector_type(8)));
typedef float f32x4 __attribute__((ext_vector_type(4)));
typedef int int4v __attribute__((ext_vector_type(4)));

__device__ __forceinline__ unsigned short f2bf(float f) {
  unsigned u = __builtin_bit_cast(unsigned, f);
  u = (u + 0x7fffu + ((u >> 16) & 1u)) >> 16;
  return (unsigned short)u;
}
__device__ __forceinline__ float bf2f(unsigned short h) {
  unsigned u = ((unsigned)h) << 16;
  return __builtin_bit_cast(float, u);
}

__device__ __forceinline__ void gload16(void* lds, const void* g) {
  __builtin_amdgcn_global_load_lds(
      (const __attribute__((address_space(1))) unsigned int*)g,
      (__attribute__((address_space(3))) unsigned int*)lds, 16, 0, 0);
}

// ---------------- fp32 -> bf16 conversion ----------------
__global__ void k_f2b(const float* __restrict__ in, unsigned short* __restrict__ out, int n4) {
  for (int i = blockIdx.x * 256 + threadIdx.x; i < n4; i += gridDim.x * 256) {
    float4 v = ((const float4*)in)[i];
    ushort4 o;
    o.x = f2bf(v.x); o.y = f2bf(v.y); o.z = f2bf(v.z); o.w = f2bf(v.w);
    ((ushort4*)out)[i] = o;
  }
}

// ---------------- transpose linear_self (5760x3840 f32) -> T (3840x5760 fp8 e4m3) ----------------
// self_pred sigma ~0.06 vs hidden sigma ~1: fp8 quantization of T adds ~0.002 abs
// noise per hidden element — negligible vs the 2% output tolerance. Halves T traffic.
__global__ __launch_bounds__(256) void k_transpose(const float* __restrict__ LS,
                                                   unsigned char* __restrict__ T) {
  __shared__ float tile[32][33];
  int tx = threadIdx.x & 31, ty = threadIdx.x >> 5;
  int c0 = blockIdx.x * 32;  // col of LS = row of T
  int r0 = blockIdx.y * 32;  // row of LS = col of T
  for (int i = ty; i < 32; i += 8)
    tile[i][tx] = LS[(size_t)(r0 + i) * LSC + c0 + tx];
  __syncthreads();
  const int i = threadIdx.x >> 3;        // T-row offset 0..31
  const int q = (threadIdx.x & 7) * 4;   // r-offset 0,4,..,28
  unsigned u = __builtin_amdgcn_cvt_pk_fp8_f32(tile[q][i], tile[q + 1][i], 0, false);
  u = __builtin_amdgcn_cvt_pk_fp8_f32(tile[q + 2][i], tile[q + 3][i], u, true);
  *(unsigned*)(T + (size_t)(c0 + i) * LSR + r0 + q) = u;
}

// ---------------- count valid[:,0] ----------------
__global__ void k_count(const int* __restrict__ ci, float* __restrict__ out) {
  int n = blockIdx.x * 256 + threadIdx.x;
  float v = (n < NROW && ci[(size_t)n * NCB] >= 0) ? 1.f : 0.f;
  #pragma unroll
  for (int m = 1; m < 64; m <<= 1) v += __shfl_xor(v, m);
  if ((threadIdx.x & 63) == 0) atomicAdd(out + 1, v);
}

// ---------------- GEMM1: 256x256 tile, BK=64 (2 k-halves), 8 waves, counted vmcnt ----------------
// r11 frozen: barrier#1 removed, counted vmcnt(8), XCD N-stripe swizzle.
__global__ __launch_bounds__(512, 2) void k_gemm1(
    const unsigned short* __restrict__ A,   // predictor bf16 [NROW][PD]
    const unsigned short* __restrict__ B,   // W1 bf16 [NH][PD]
    const float* __restrict__ b1,
    unsigned short* __restrict__ H) {       // out [NROW][NH]
  __shared__ int4 Al[2][2][1024];   // 64 KB
  __shared__ int4 Bl[2][2][1024];   // 64 KB

  const int tid = threadIdx.x;
  const int lane = tid & 63;
  const int w = tid >> 6;             // 0..7
  const int wr = w >> 2, wc = w & 3;  // wave grid 2(M) x 4(N)
  const int l15 = lane & 15, hi = lane >> 4;
  const int w64 = tid & ~63;

  // XCD swizzle: grid 1536 = 64 mt x 24 nt; each XCD owns 3 nt (3MB B -> L2)
  const int bid = blockIdx.x;
  const int xcd = bid & 7, p = bid >> 3;   // p in [0,192)
  const int nt = xcd * 3 + p % 3;
  const int mt = p / 3;
  const int tm = mt * 256, tn = nt * 256;

  f32x4 acc[8][4] = {};

  auto STAGE = [&](int buf, int t, int kh) {
    const int kb = t * 64 + kh * 32;
    #pragma unroll
    for (int g = 0; g < 2; ++g) {
      const int slot = g * 512 + tid;
      const int row = slot >> 2;                       // 0..255
      const int lc = (slot & 3) ^ ((row >> 1) & 3);    // inverse-swizzled source col
      gload16(&Al[buf][kh][g * 512 + w64], A + (size_t)(tm + row) * PD + kb + lc * 8);
      gload16(&Bl[buf][kh][g * 512 + w64], B + (size_t)(tn + row) * PD + kb + lc * 8);
    }
  };

  // prologue: t0.kh0, t0.kh1, t1.kh0 -> 12 loads; wait oldest 4 (t0.kh0)
  STAGE(0, 0, 0);
  STAGE(0, 0, 1);
  STAGE(1, 1, 0);
  asm volatile("s_waitcnt vmcnt(8)" ::: "memory");
  __builtin_amdgcn_s_barrier();

  for (int t = 0; t < GNT; ++t) {
    const int buf = t & 1;
    #pragma unroll
    for (int kh = 0; kh < 2; ++kh) {
      // frag reads (swizzled)
      int4 af[8], bfr[4];
      #pragma unroll
      for (int mi = 0; mi < 8; ++mi) {
        const int row = wr * 128 + mi * 16 + l15;
        const int pc = hi ^ ((row >> 1) & 3);
        af[mi] = Al[buf][kh][row * 4 + pc];
      }
      #pragma unroll
      for (int ni = 0; ni < 4; ++ni) {
        const int row = wc * 64 + ni * 16 + l15;
        const int pc = hi ^ ((row >> 1) & 3);
        bfr[ni] = Bl[buf][kh][row * 4 + pc];
      }
      // stage (regions race-safe, r7 audit)
      if (kh == 0) {
        if (t + 1 < GNT) STAGE(buf ^ 1, t + 1, 1);
      } else {
        if (t + 2 < GNT) STAGE(buf, t + 2, 0);
      }
      // (barrier #1 removed — cross-wave LDS/VALU vs MFMA overlap)
      __builtin_amdgcn_s_setprio(1);
      #pragma unroll
      for (int mi = 0; mi < 8; ++mi)
        #pragma unroll
        for (int ni = 0; ni < 4; ++ni)
          acc[mi][ni] = __builtin_amdgcn_mfma_f32_16x16x32_bf16(
              __builtin_bit_cast(bf16x8, af[mi]), __builtin_bit_cast(bf16x8, bfr[ni]),
              acc[mi][ni], 0, 0, 0);
      __builtin_amdgcn_s_setprio(0);
      // counted drains (audited): A-phase needs t.kh1; B-phase needs (t+1).kh0
      if (kh == 0) {
        if (t < GNT - 1) asm volatile("s_waitcnt vmcnt(8)" ::: "memory");
        else             asm volatile("s_waitcnt vmcnt(0)" ::: "memory");
      } else {
        if (t < GNT - 2)      asm volatile("s_waitcnt vmcnt(8)" ::: "memory");
        else if (t == GNT - 2) asm volatile("s_waitcnt vmcnt(4)" ::: "memory");
      }
      __builtin_amdgcn_s_barrier();
    }
  }

  // epilogue: bias + NT store
  #pragma unroll
  for (int ni = 0; ni < 4; ++ni) {
    const int col = tn + wc * 64 + ni * 16 + l15;
    const float bb = b1[col];
    #pragma unroll
    for (int mi = 0; mi < 8; ++mi)
      #pragma unroll
      for (int reg = 0; reg < 4; ++reg) {
        const int row = tm + wr * 128 + mi * 16 + hi * 4 + reg;
        __builtin_nontemporal_store(f2bf(acc[mi][ni][reg] + bb),
                                    H + (size_t)row * NH + col);
      }
  }
}

// ---------------- self-pred gather: branch-free unrolled, fp8 T ----------------
template <int KM>
__device__ __forceinline__ void gather_chunk(
    const unsigned char* __restrict__ T, const int* idxrow,
    int oo, int bbv, float v[8]) {
  #pragma unroll
  for (int kc = 0; kc < KM; ++kc) {
    int c = idxrow[kc];
    float m = (c >= 0 && kc <= bbv) ? 1.f : 0.f;
    int cc = c < 0 ? 0 : (c >= CS ? CS - 1 : c);
    int2 tv = *(const int2*)(T + (size_t)(kc * CS + cc) * LSR + oo);  // 8 fp8
    float f[8];
    f[0] = __builtin_amdgcn_cvt_f32_fp8(tv.x, 0);
    f[1] = __builtin_amdgcn_cvt_f32_fp8(tv.x, 1);
    f[2] = __builtin_amdgcn_cvt_f32_fp8(tv.x, 2);
    f[3] = __builtin_amdgcn_cvt_f32_fp8(tv.x, 3);
    f[4] = __builtin_amdgcn_cvt_f32_fp8(tv.y, 0);
    f[5] = __builtin_amdgcn_cvt_f32_fp8(tv.y, 1);
    f[6] = __builtin_amdgcn_cvt_f32_fp8(tv.y, 2);
    f[7] = __builtin_amdgcn_cvt_f32_fp8(tv.y, 3);
    #pragma unroll
    for (int e = 0; e < 8; ++e) v[e] = fmaf(m, f[e], v[e]);
  }
}

// grid = dim3(3, SA_NBLK): x = 2048-col stripe (compile-time gather depth),
// y = 32-row block. 1536 blocks -> 6/CU. One 8-col chunk per thread per row.
__global__ __launch_bounds__(256) void k_selfadd(
    unsigned short* __restrict__ H,        // [NROW][NH] bf16, in-place
    const unsigned char* __restrict__ T,   // [LSC][LSR] fp8 (linear_self^T)
    const int* __restrict__ ci,
    float* __restrict__ partials) {        // [2][SA_NBLK][NH]
  __shared__ int idxs[SA_ROWS][NCB];
  const int tid = threadIdx.x;
  const int row0 = blockIdx.y * SA_ROWS;
  const int sx = blockIdx.x;               // 0..2, block-uniform
  for (int i = tid; i < SA_ROWS * NCB; i += 256)
    idxs[i >> 4][i & 15] = ci[(size_t)(row0 + (i >> 4)) * NCB + (i & 15)];
  __syncthreads();

  const int col0 = sx * 2048 + tid * 8;
  const int o = col0 - HD;
  const int oo = o < 0 ? 0 : o;
  const int bb = o < 0 ? -1 : o / HD;

  float cs[8] = {0}, cq[8] = {0};

  for (int rr = 0; rr < SA_ROWS; ++rr) {
    const size_t ro = (size_t)(row0 + rr) * NH;
    int4v hv = __builtin_nontemporal_load((const int4v*)(H + ro + col0));
    const unsigned short* hs = (const unsigned short*)&hv;
    float v[8];
    #pragma unroll
    for (int e = 0; e < 8; ++e) v[e] = bf2f(hs[e]);
    switch (sx) {  // block-uniform branch, compile-time gather depth
      case 0: gather_chunk<5>(T, idxs[rr], oo, bb, v); break;
      case 1: gather_chunk<10>(T, idxs[rr], oo, bb, v); break;
      default: gather_chunk<15>(T, idxs[rr], oo, bb, v); break;
    }
    unsigned short os[8];
    #pragma unroll
    for (int e = 0; e < 8; ++e) {
      float x = fmaxf(v[e], 0.f);
      unsigned short hb = f2bf(x);
      os[e] = hb;
      float xr = bf2f(hb);
      cs[e] += xr;
      cq[e] += xr * xr;
    }
    // NT store: keep T resident in L2/L3; passc re-fetches H from HBM anyway
    __builtin_nontemporal_store(*(const int4v*)os, (int4v*)(H + ro + col0));
  }

  float* Ps = partials + (size_t)blockIdx.y * NH + col0;
  float* Pq = partials + (size_t)(SA_NBLK + blockIdx.y) * NH + col0;
  float4 a = {cs[0], cs[1], cs[2], cs[3]};
  float4 b4 = {cs[4], cs[5], cs[6], cs[7]};
  *(float4*)Ps = a; *(float4*)(Ps + 4) = b4;
  float4 c4 = {cq[0], cq[1], cq[2], cq[3]};
  float4 d4 = {cq[4], cq[5], cq[6], cq[7]};
  *(float4*)Pq = c4; *(float4*)(Pq + 4) = d4;
}

// ---------------- reduce partials -> colsum/colsq ----------------
// grid dim3(NH/256, 8)
__global__ void k_red(const float* __restrict__ partials,
                      float* __restrict__ colsum, float* __restrict__ colsq) {
  int j = blockIdx.x * 256 + threadIdx.x;
  const float* Ps = partials;
  const float* Pq = partials + (size_t)SA_NBLK * NH;
  float s = 0.f, q = 0.f;
  const int b0 = blockIdx.y * (SA_NBLK / 8), b1 = b0 + SA_NBLK / 8;
  for (int by = b0; by < b1; ++by) {
    s += Ps[(size_t)by * NH + j];
    q += Pq[(size_t)by * NH + j];
  }
  atomicAdd(colsum + j, s);
  atomicAdd(colsq + j, q);
}

// ---------------- BN params ----------------
__global__ void k_bn(const float* __restrict__ colsum, const float* __restrict__ colsq,
                     const float* __restrict__ gamma, const float* __restrict__ beta,
                     float* __restrict__ scale, float* __restrict__ shift) {
  int j = blockIdx.x * 256 + threadIdx.x;
  if (j >= NH) return;
  float mean = colsum[j] * (1.f / NROW);
  float var = colsq[j] * (1.f / NROW) - mean * mean;
  var = fmaxf(var, 0.f);
  float rs = rsqrtf(var + 1e-5f);
  float g = gamma[j] * rs;
  scale[j] = g;
  shift[j] = beta[j] - mean * g;
}

// ---------------- fold BN into linear2/bias2 ----------------
__global__ __launch_bounds__(128) void k_fold(
    const float* __restrict__ L2, const float* __restrict__ bias2,
    const float* __restrict__ scale, const float* __restrict__ shift,
    unsigned short* __restrict__ L2b, float* __restrict__ bias2p) {
  __shared__ float red[2];
  int kc = blockIdx.x;        // k*256 + c
  int k = kc >> 8;
  size_t off = (size_t)kc * HD;
  float a = 0.f;
  for (int h = threadIdx.x; h < HD; h += 128) {
    float wv = L2[off + h];
    int jh = k * HD + h;
    L2b[off + h] = f2bf(wv * scale[jh]);
    a += wv * shift[jh];
  }
  #pragma unroll
  for (int m = 1; m < 64; m <<= 1) a += __shfl_xor(a, m);
  if ((threadIdx.x & 63) == 0) red[threadIdx.x >> 6] = a;
  __syncthreads();
  if (threadIdx.x == 0) bias2p[kc] = bias2[kc] + red[0] + red[1];
}

// ---------------- pass C: logits GEMM + log-softmax + target gather ----------------
// grid dim3(256,16); XCD swizzle (2 codebooks/XCD -> L2b panels L2-resident).
// 3-region LDS rotation with counted vmcnt(5): stage 2 phases ahead, raw
// s_barrier per phase (no full drain).
__global__ __launch_bounds__(256, 2) void k_passc(
    const unsigned short* __restrict__ H,     // [NROW][NH] bf16
    const unsigned short* __restrict__ L2b,   // [NCB][CS][HD] bf16 (BN-folded)
    const float* __restrict__ bias2p,         // [NCB][CS]
    const int* __restrict__ ci,
    float* __restrict__ out) {
  __shared__ char smem[64 * 260 * 4];  // 66560B; 3x20480 staging aliased under lg
  __shared__ float red[4];
  float* lg = (float*)smem;            // [64][260]

  const int tid = threadIdx.x, lane = tid & 63, w = tid >> 6;
  const int bidf = blockIdx.y * gridDim.x + blockIdx.x;  // 0..4095
  const int xcd = bidf & 7, p = bidf >> 3;               // p in [0,512)
  const int k = xcd * 2 + (p & 1);
  const int tm = (p >> 1) * 64;
  const int r = lane & 15, kg = lane >> 4;

  auto Asb = [&](int r3) { return (int4*)(smem + r3 * 20480); };          // 4KB
  auto Bsb = [&](int r3) { return (int4*)(smem + r3 * 20480 + 4096); };   // 16KB

  const int s0r = (w * 64 + lane) & 63, s0g = (w * 64 + lane) >> 6;
  auto STAGE = [&](int r3, int kk) {
    const int k0 = kk * 32;
    gload16(Asb(r3) + w * 64, H + (size_t)(tm + s0r) * NH + k * HD + k0 + s0g * 8);
    #pragma unroll
    for (int i = 0; i < 4; ++i) {
      int s = i * 256 + w * 64 + lane;
      int srow = s & 255, skg = s >> 8;
      gload16(Bsb(r3) + i * 256 + w * 64,
              L2b + (size_t)(k * CS + srow) * HD + k0 + skg * 8);
    }
  };

  f32x4 acc[4][4] = {};
  STAGE(0, 0);
  STAGE(1, 1);
  asm volatile("s_waitcnt vmcnt(5)" ::: "memory");   // region 0 landed
  __builtin_amdgcn_s_barrier();

  for (int kk = 0; kk < HD / 32; ++kk) {  // 12 phases
    const int r3 = kk % 3;
    int4 af[4], bfr[4];
    #pragma unroll
    for (int mi = 0; mi < 4; ++mi) af[mi] = Asb(r3)[kg * 64 + mi * 16 + r];
    #pragma unroll
    for (int ni = 0; ni < 4; ++ni) bfr[ni] = Bsb(r3)[kg * 256 + w * 64 + ni * 16 + r];
    if (kk + 2 < HD / 32) STAGE((kk + 2) % 3, kk + 2);   // overwrites region read at kk-1
    __builtin_amdgcn_s_setprio(1);
    #pragma unroll
    for (int mi = 0; mi < 4; ++mi)
      #pragma unroll
      for (int ni = 0; ni < 4; ++ni)
        acc[mi][ni] = __builtin_amdgcn_mfma_f32_16x16x32_bf16(
            __builtin_bit_cast(bf16x8, af[mi]), __builtin_bit_cast(bf16x8, bfr[ni]),
            acc[mi][ni], 0, 0, 0);
    __builtin_amdgcn_s_setprio(0);
    if (kk + 1 < HD / 32) {
      if (kk + 2 < HD / 32) asm volatile("s_waitcnt vmcnt(5)" ::: "memory");
      else                  asm volatile("s_waitcnt vmcnt(0)" ::: "memory");
    }
    __builtin_amdgcn_s_barrier();
  }

  const int lr0 = (lane >> 4) * 4;
  #pragma unroll
  for (int mi = 0; mi < 4; ++mi)
    #pragma unroll
    for (int ni = 0; ni < 4; ++ni) {
      int col = w * 64 + ni * 16 + r;
      float bb = bias2p[k * CS + col];
      #pragma unroll
      for (int reg = 0; reg < 4; ++reg) {
        int row = mi * 16 + lr0 + reg;
        lg[row * 260 + col] = acc[mi][ni][reg] + bb;
      }
    }
  __syncthreads();

  int row = tid >> 2, part = tid & 3;
  const float4* rp = (const float4*)(lg + row * 260 + part * 64);
  float s = 0.f;
  #pragma unroll
  for (int i = 0; i < 16; ++i) {
    float4 v = rp[i];
    s += __expf(v.x) + __expf(v.y) + __expf(v.z) + __expf(v.w);
  }
  s += __shfl_xor(s, 1);
  s += __shfl_xor(s, 2);
  float contrib = 0.f;
  if (part == 0) {
    float lse = __logf(s);
    int c = ci[(size_t)(tm + row) * NCB + k];
    if (c >= 0) {
      c = c < CS ? c : CS - 1;
      contrib = lg[row * 260 + c] - lse;
    }
  }
  #pragma unroll
  for (int msk = 1; msk < 64; msk <<= 1) contrib += __shfl_xor(contrib, msk);
  if (lane == 0) red[w] = contrib;
  __syncthreads();
  if (tid == 0) atomicAdd(out, red[0] + red[1] + red[2] + red[3]);
}

extern "C" void kernel_launch(void* const* d_in, const int* in_sizes, int n_in,
                              void* d_out, int out_size, void* d_ws, size_t ws_size,
                              hipStream_t stream) {
  const float* predictor = (const float*)d_in[0];
  const int* cbidx       = (const int*)d_in[1];
  const float* W1        = (const float*)d_in[2];
  const float* b1        = (const float*)d_in[3];
  const float* lself     = (const float*)d_in[4];
  const float* gamma     = (const float*)d_in[5];
  const float* beta      = (const float*)d_in[6];
  const float* L2        = (const float*)d_in[7];
  const float* bias2     = (const float*)d_in[8];
  float* out = (float*)d_out;

  char* ws = (char*)d_ws;
  size_t off = 0;
  auto alloc = [&](size_t bytes) {
    char* p = ws + off;
    off += (bytes + 255) & ~(size_t)255;
    return p;
  };
  unsigned short* predB  = (unsigned short*)alloc((size_t)NROW * PD * 2);
  unsigned short* W1B    = (unsigned short*)alloc((size_t)NH * PD * 2);
  unsigned char*  T      = (unsigned char*)alloc((size_t)LSC * LSR);
  unsigned short* Hb     = (unsigned short*)alloc((size_t)NROW * NH * 2);
  unsigned short* L2b    = (unsigned short*)alloc((size_t)NCB * CS * HD * 2);
  float* partials = (float*)alloc((size_t)2 * SA_NBLK * NH * 4);
  float* colsum = (float*)alloc(NH * 4);
  float* colsq  = (float*)alloc(NH * 4);
  float* scale  = (float*)alloc(NH * 4);
  float* shift  = (float*)alloc(NH * 4);
  float* bias2p = (float*)alloc(NCB * CS * 4);

  hipMemsetAsync(d_out, 0, 2 * sizeof(float), stream);
  hipMemsetAsync(colsum, 0, NH * 4, stream);
  hipMemsetAsync(colsq, 0, NH * 4, stream);

  k_f2b<<<2048, 256, 0, stream>>>(predictor, predB, NROW * PD / 4);
  k_f2b<<<2048, 256, 0, stream>>>(W1, W1B, NH * PD / 4);
  k_transpose<<<dim3(LSC / 32, LSR / 32), 256, 0, stream>>>(lself, T);
  k_count<<<NROW / 256, 256, 0, stream>>>(cbidx, out);
  k_gemm1<<<(NROW / 256) * (NH / 256), 512, 0, stream>>>(predB, W1B, b1, Hb);
  k_selfadd<<<dim3(3, SA_NBLK), 256, 0, stream>>>(Hb, T, cbidx, partials);
  k_red<<<dim3(NH / 256, 8), 256, 0, stream>>>(partials, colsum, colsq);
  k_bn<<<NH / 256, 256, 0, stream>>>(colsum, colsq, gamma, beta, scale, shift);
  k_fold<<<NCB * CS, 128, 0, stream>>>(L2, bias2, scale, shift, L2b, bias2p);
  k_passc<<<dim3(NROW / 64, NCB), 256, 0, stream>>>(Hb, L2b, bias2p, cbidx, out);
}

// Round 15
// 855.970 us; speedup vs baseline: 1.3480x; 1.1142x over previous
//
#include <hip/hip_runtime.h>
#include <hip/hip_bf16.h>

#define NCB 16
#define CS 256
#define HD 384
#define PD 2048
#define NROW 16384
#define NH 6144      // NCB*HD
#define LSR 5760     // (NCB-1)*HD  rows of linear_self
#define LSC 3840     // (NCB-1)*CS  cols of linear_self
#define SA_ROWS 32
#define SA_NBLK (NROW / SA_ROWS)   // 512
#define GNT (PD / 128)             // 16 K-tiles for fp8 gemm1 (BK=128)

typedef __bf16 bf16x8 __attribute__((ext_vector_type(8)));
typedef float f32x4 __attribute__((ext_vector_type(4)));
typedef int int4v __attribute__((ext_vector_type(4)));
typedef int int2v __attribute__((ext_vector_type(2)));

__device__ __forceinline__ unsigned short f2bf(float f) {
  unsigned u = __builtin_bit_cast(unsigned, f);
  u = (u + 0x7fffu + ((u >> 16) & 1u)) >> 16;
  return (unsigned short)u;
}
__device__ __forceinline__ float bf2f(unsigned short h) {
  unsigned u = ((unsigned)h) << 16;
  return __builtin_bit_cast(float, u);
}

__device__ __forceinline__ void gload16(void* lds, const void* g) {
  __builtin_amdgcn_global_load_lds(
      (const __attribute__((address_space(1))) unsigned int*)g,
      (__attribute__((address_space(3))) unsigned int*)lds, 16, 0, 0);
}

// ---------------- fp32 -> fp8 e4m3 conversion (8 elements/thread/iter) ----------------
__global__ void k_f2b8(const float* __restrict__ in, unsigned* __restrict__ out, int n8) {
  for (int i = blockIdx.x * 256 + threadIdx.x; i < n8; i += gridDim.x * 256) {
    float4 a = ((const float4*)in)[i * 2];
    float4 b = ((const float4*)in)[i * 2 + 1];
    unsigned lo = __builtin_amdgcn_cvt_pk_fp8_f32(a.x, a.y, 0, false);
    lo = __builtin_amdgcn_cvt_pk_fp8_f32(a.z, a.w, lo, true);
    unsigned hi = __builtin_amdgcn_cvt_pk_fp8_f32(b.x, b.y, 0, false);
    hi = __builtin_amdgcn_cvt_pk_fp8_f32(b.z, b.w, hi, true);
    uint2 o = {lo, hi};
    ((uint2*)out)[i] = o;
  }
}

// ---------------- transpose linear_self (5760x3840 f32) -> T (3840x5760 fp8 e4m3) ----------------
__global__ __launch_bounds__(256) void k_transpose(const float* __restrict__ LS,
                                                   unsigned char* __restrict__ T) {
  __shared__ float tile[32][33];
  int tx = threadIdx.x & 31, ty = threadIdx.x >> 5;
  int c0 = blockIdx.x * 32;  // col of LS = row of T
  int r0 = blockIdx.y * 32;  // row of LS = col of T
  for (int i = ty; i < 32; i += 8)
    tile[i][tx] = LS[(size_t)(r0 + i) * LSC + c0 + tx];
  __syncthreads();
  const int i = threadIdx.x >> 3;        // T-row offset 0..31
  const int q = (threadIdx.x & 7) * 4;   // r-offset 0,4,..,28
  unsigned u = __builtin_amdgcn_cvt_pk_fp8_f32(tile[q][i], tile[q + 1][i], 0, false);
  u = __builtin_amdgcn_cvt_pk_fp8_f32(tile[q + 2][i], tile[q + 3][i], u, true);
  *(unsigned*)(T + (size_t)(c0 + i) * LSR + r0 + q) = u;
}

// ---------------- count valid[:,0] ----------------
__global__ void k_count(const int* __restrict__ ci, float* __restrict__ out) {
  int n = blockIdx.x * 256 + threadIdx.x;
  float v = (n < NROW && ci[(size_t)n * NCB] >= 0) ? 1.f : 0.f;
  #pragma unroll
  for (int m = 1; m < 64; m <<= 1) v += __shfl_xor(v, m);
  if ((threadIdx.x & 63) == 0) atomicAdd(out + 1, v);
}

// ---------------- GEMM1 (fp8): 256x256 tile, BK=128 (2 k-halves of 64), 8 waves ----------------
// r11 skeleton byte-for-byte on LDS/staging/vmcnt; fp8 doubles K per 16B granule:
// each b128 frag = K=64 -> 2 MFMAs (bytes 0-7 then 8-15; same k-permutation applied
// to A and B, so the sum over k is unchanged). GNT halves; MFMA/window doubles.
__global__ __launch_bounds__(512, 2) void k_gemm1(
    const unsigned char* __restrict__ A,   // predictor fp8 [NROW][PD]
    const unsigned char* __restrict__ B,   // W1 fp8 [NH][PD]
    const float* __restrict__ b1,
    unsigned short* __restrict__ H) {      // out [NROW][NH] bf16
  __shared__ int4v Al[2][2][1024];   // [buf][kh][row*4+pc] 16B granules (64 KB)
  __shared__ int4v Bl[2][2][1024];

  const int tid = threadIdx.x;
  const int lane = tid & 63;
  const int w = tid >> 6;             // 0..7
  const int wr = w >> 2, wc = w & 3;  // wave grid 2(M) x 4(N)
  const int l15 = lane & 15, hi = lane >> 4;
  const int w64 = tid & ~63;

  // XCD swizzle: grid 1536 = 64 mt x 24 nt; each XCD owns 3 nt
  const int bid = blockIdx.x;
  const int xcd = bid & 7, p = bid >> 3;   // p in [0,192)
  const int nt = xcd * 3 + p % 3;
  const int mt = p / 3;
  const int tm = mt * 256, tn = nt * 256;

  f32x4 acc[8][4] = {};

  auto STAGE = [&](int buf, int t, int kh) {
    const int kb = t * 128 + kh * 64;   // byte offset along K
    #pragma unroll
    for (int g = 0; g < 2; ++g) {
      const int slot = g * 512 + tid;
      const int row = slot >> 2;                       // 0..255
      const int lc = (slot & 3) ^ ((row >> 1) & 3);    // inverse-swizzled source granule
      gload16(&Al[buf][kh][g * 512 + w64], A + (size_t)(tm + row) * PD + kb + lc * 16);
      gload16(&Bl[buf][kh][g * 512 + w64], B + (size_t)(tn + row) * PD + kb + lc * 16);
    }
  };

  // prologue: t0.kh0, t0.kh1, t1.kh0 -> 12 loads; wait oldest 4 (t0.kh0)
  STAGE(0, 0, 0);
  STAGE(0, 0, 1);
  STAGE(1, 1, 0);
  asm volatile("s_waitcnt vmcnt(8)" ::: "memory");
  __builtin_amdgcn_s_barrier();

  for (int t = 0; t < GNT; ++t) {
    const int buf = t & 1;
    #pragma unroll
    for (int kh = 0; kh < 2; ++kh) {
      // frag reads (swizzled, b128 each = K=64 of fp8)
      int4v af[8], bfr[4];
      #pragma unroll
      for (int mi = 0; mi < 8; ++mi) {
        const int row = wr * 128 + mi * 16 + l15;
        const int pc = hi ^ ((row >> 1) & 3);
        af[mi] = Al[buf][kh][row * 4 + pc];
      }
      #pragma unroll
      for (int ni = 0; ni < 4; ++ni) {
        const int row = wc * 64 + ni * 16 + l15;
        const int pc = hi ^ ((row >> 1) & 3);
        bfr[ni] = Bl[buf][kh][row * 4 + pc];
      }
      // stage prefetch (regions race-safe, r7/r11 audit; same loads/STAGE)
      if (kh == 0) {
        if (t + 1 < GNT) STAGE(buf ^ 1, t + 1, 1);
      } else {
        if (t + 2 < GNT) STAGE(buf, t + 2, 0);
      }
      // (barrier #1 removed — cross-wave LDS/VALU vs MFMA overlap)
      __builtin_amdgcn_s_setprio(1);
      #pragma unroll
      for (int mi = 0; mi < 8; ++mi) {
        int2v alo_, ahi_;
        alo_[0] = af[mi][0]; alo_[1] = af[mi][1];
        ahi_[0] = af[mi][2]; ahi_[1] = af[mi][3];
        const long a1 = __builtin_bit_cast(long, alo_);
        const long a2 = __builtin_bit_cast(long, ahi_);
        #pragma unroll
        for (int ni = 0; ni < 4; ++ni) {
          int2v blo_, bhi_;
          blo_[0] = bfr[ni][0]; blo_[1] = bfr[ni][1];
          bhi_[0] = bfr[ni][2]; bhi_[1] = bfr[ni][3];
          acc[mi][ni] = __builtin_amdgcn_mfma_f32_16x16x32_fp8_fp8(
              a1, __builtin_bit_cast(long, blo_), acc[mi][ni], 0, 0, 0);
          acc[mi][ni] = __builtin_amdgcn_mfma_f32_16x16x32_fp8_fp8(
              a2, __builtin_bit_cast(long, bhi_), acc[mi][ni], 0, 0, 0);
        }
      }
      __builtin_amdgcn_s_setprio(0);
      // counted drains (audited): A-phase needs t.kh1; B-phase needs (t+1).kh0
      if (kh == 0) {
        if (t < GNT - 1) asm volatile("s_waitcnt vmcnt(8)" ::: "memory");
        else             asm volatile("s_waitcnt vmcnt(0)" ::: "memory");
      } else {
        if (t < GNT - 2)      asm volatile("s_waitcnt vmcnt(8)" ::: "memory");
        else if (t == GNT - 2) asm volatile("s_waitcnt vmcnt(4)" ::: "memory");
      }
      __builtin_amdgcn_s_barrier();
    }
  }

  // epilogue: bias + NT store
  #pragma unroll
  for (int ni = 0; ni < 4; ++ni) {
    const int col = tn + wc * 64 + ni * 16 + l15;
    const float bb = b1[col];
    #pragma unroll
    for (int mi = 0; mi < 8; ++mi)
      #pragma unroll
      for (int reg = 0; reg < 4; ++reg) {
        const int row = tm + wr * 128 + mi * 16 + hi * 4 + reg;
        __builtin_nontemporal_store(f2bf(acc[mi][ni][reg] + bb),
                                    H + (size_t)row * NH + col);
      }
  }
}

// ---------------- self-pred gather: branch-free unrolled, fp8 T ----------------
template <int KM>
__device__ __forceinline__ void gather_chunk(
    const unsigned char* __restrict__ T, const int* idxrow,
    int oo, int bbv, float v[8]) {
  #pragma unroll
  for (int kc = 0; kc < KM; ++kc) {
    int c = idxrow[kc];
    float m = (c >= 0 && kc <= bbv) ? 1.f : 0.f;
    int cc = c < 0 ? 0 : (c >= CS ? CS - 1 : c);
    int2 tv = *(const int2*)(T + (size_t)(kc * CS + cc) * LSR + oo);  // 8 fp8
    float f[8];
    f[0] = __builtin_amdgcn_cvt_f32_fp8(tv.x, 0);
    f[1] = __builtin_amdgcn_cvt_f32_fp8(tv.x, 1);
    f[2] = __builtin_amdgcn_cvt_f32_fp8(tv.x, 2);
    f[3] = __builtin_amdgcn_cvt_f32_fp8(tv.x, 3);
    f[4] = __builtin_amdgcn_cvt_f32_fp8(tv.y, 0);
    f[5] = __builtin_amdgcn_cvt_f32_fp8(tv.y, 1);
    f[6] = __builtin_amdgcn_cvt_f32_fp8(tv.y, 2);
    f[7] = __builtin_amdgcn_cvt_f32_fp8(tv.y, 3);
    #pragma unroll
    for (int e = 0; e < 8; ++e) v[e] = fmaf(m, f[e], v[e]);
  }
}

// grid = dim3(3, SA_NBLK): x = 2048-col stripe (compile-time gather depth),
// y = 32-row block. 1536 blocks -> 6/CU. One 8-col chunk per thread per row.
__global__ __launch_bounds__(256) void k_selfadd(
    unsigned short* __restrict__ H,        // [NROW][NH] bf16, in-place
    const unsigned char* __restrict__ T,   // [LSC][LSR] fp8 (linear_self^T)
    const int* __restrict__ ci,
    float* __restrict__ partials) {        // [2][SA_NBLK][NH]
  __shared__ int idxs[SA_ROWS][NCB];
  const int tid = threadIdx.x;
  const int row0 = blockIdx.y * SA_ROWS;
  const int sx = blockIdx.x;               // 0..2, block-uniform
  for (int i = tid; i < SA_ROWS * NCB; i += 256)
    idxs[i >> 4][i & 15] = ci[(size_t)(row0 + (i >> 4)) * NCB + (i & 15)];
  __syncthreads();

  const int col0 = sx * 2048 + tid * 8;
  const int o = col0 - HD;
  const int oo = o < 0 ? 0 : o;
  const int bb = o < 0 ? -1 : o / HD;

  float cs[8] = {0}, cq[8] = {0};

  for (int rr = 0; rr < SA_ROWS; ++rr) {
    const size_t ro = (size_t)(row0 + rr) * NH;
    int4v hv = __builtin_nontemporal_load((const int4v*)(H + ro + col0));
    const unsigned short* hs = (const unsigned short*)&hv;
    float v[8];
    #pragma unroll
    for (int e = 0; e < 8; ++e) v[e] = bf2f(hs[e]);
    switch (sx) {  // block-uniform branch, compile-time gather depth
      case 0: gather_chunk<5>(T, idxs[rr], oo, bb, v); break;
      case 1: gather_chunk<10>(T, idxs[rr], oo, bb, v); break;
      default: gather_chunk<15>(T, idxs[rr], oo, bb, v); break;
    }
    unsigned short os[8];
    #pragma unroll
    for (int e = 0; e < 8; ++e) {
      float x = fmaxf(v[e], 0.f);
      unsigned short hb = f2bf(x);
      os[e] = hb;
      float xr = bf2f(hb);
      cs[e] += xr;
      cq[e] += xr * xr;
    }
    // NT store: keep T resident in L2/L3; passc re-fetches H from HBM anyway
    __builtin_nontemporal_store(*(const int4v*)os, (int4v*)(H + ro + col0));
  }

  float* Ps = partials + (size_t)blockIdx.y * NH + col0;
  float* Pq = partials + (size_t)(SA_NBLK + blockIdx.y) * NH + col0;
  float4 a = {cs[0], cs[1], cs[2], cs[3]};
  float4 b4 = {cs[4], cs[5], cs[6], cs[7]};
  *(float4*)Ps = a; *(float4*)(Ps + 4) = b4;
  float4 c4 = {cq[0], cq[1], cq[2], cq[3]};
  float4 d4 = {cq[4], cq[5], cq[6], cq[7]};
  *(float4*)Pq = c4; *(float4*)(Pq + 4) = d4;
}

// ---------------- reduce partials -> colsum/colsq ----------------
// grid dim3(NH/256, 8)
__global__ void k_red(const float* __restrict__ partials,
                      float* __restrict__ colsum, float* __restrict__ colsq) {
  int j = blockIdx.x * 256 + threadIdx.x;
  const float* Ps = partials;
  const float* Pq = partials + (size_t)SA_NBLK * NH;
  float s = 0.f, q = 0.f;
  const int b0 = blockIdx.y * (SA_NBLK / 8), b1 = b0 + SA_NBLK / 8;
  for (int by = b0; by < b1; ++by) {
    s += Ps[(size_t)by * NH + j];
    q += Pq[(size_t)by * NH + j];
  }
  atomicAdd(colsum + j, s);
  atomicAdd(colsq + j, q);
}

// ---------------- BN params ----------------
__global__ void k_bn(const float* __restrict__ colsum, const float* __restrict__ colsq,
                     const float* __restrict__ gamma, const float* __restrict__ beta,
                     float* __restrict__ scale, float* __restrict__ shift) {
  int j = blockIdx.x * 256 + threadIdx.x;
  if (j >= NH) return;
  float mean = colsum[j] * (1.f / NROW);
  float var = colsq[j] * (1.f / NROW) - mean * mean;
  var = fmaxf(var, 0.f);
  float rs = rsqrtf(var + 1e-5f);
  float g = gamma[j] * rs;
  scale[j] = g;
  shift[j] = beta[j] - mean * g;
}

// ---------------- fold BN into linear2/bias2 ----------------
__global__ __launch_bounds__(128) void k_fold(
    const float* __restrict__ L2, const float* __restrict__ bias2,
    const float* __restrict__ scale, const float* __restrict__ shift,
    unsigned short* __restrict__ L2b, float* __restrict__ bias2p) {
  __shared__ float red[2];
  int kc = blockIdx.x;        // k*256 + c
  int k = kc >> 8;
  size_t off = (size_t)kc * HD;
  float a = 0.f;
  for (int h = threadIdx.x; h < HD; h += 128) {
    float wv = L2[off + h];
    int jh = k * HD + h;
    L2b[off + h] = f2bf(wv * scale[jh]);
    a += wv * shift[jh];
  }
  #pragma unroll
  for (int m = 1; m < 64; m <<= 1) a += __shfl_xor(a, m);
  if ((threadIdx.x & 63) == 0) red[threadIdx.x >> 6] = a;
  __syncthreads();
  if (threadIdx.x == 0) bias2p[kc] = bias2[kc] + red[0] + red[1];
}

// ---------------- pass C: logits GEMM + log-softmax + target gather ----------------
// grid dim3(256,16); XCD swizzle (2 codebooks/XCD -> L2b panels L2-resident).
// 3-region LDS rotation with counted vmcnt(5); single-pass softmax.
__global__ __launch_bounds__(256, 2) void k_passc(
    const unsigned short* __restrict__ H,     // [NROW][NH] bf16
    const unsigned short* __restrict__ L2b,   // [NCB][CS][HD] bf16 (BN-folded)
    const float* __restrict__ bias2p,         // [NCB][CS]
    const int* __restrict__ ci,
    float* __restrict__ out) {
  __shared__ char smem[64 * 260 * 4];  // 66560B; 3x20480 staging aliased under lg
  __shared__ float red[4];
  float* lg = (float*)smem;            // [64][260]

  const int tid = threadIdx.x, lane = tid & 63, w = tid >> 6;
  const int bidf = blockIdx.y * gridDim.x + blockIdx.x;  // 0..4095
  const int xcd = bidf & 7, p = bidf >> 3;               // p in [0,512)
  const int k = xcd * 2 + (p & 1);
  const int tm = (p >> 1) * 64;
  const int r = lane & 15, kg = lane >> 4;

  auto Asb = [&](int r3) { return (int4*)(smem + r3 * 20480); };          // 4KB
  auto Bsb = [&](int r3) { return (int4*)(smem + r3 * 20480 + 4096); };   // 16KB

  const int s0r = (w * 64 + lane) & 63, s0g = (w * 64 + lane) >> 6;
  auto STAGE = [&](int r3, int kk) {
    const int k0 = kk * 32;
    gload16(Asb(r3) + w * 64, H + (size_t)(tm + s0r) * NH + k * HD + k0 + s0g * 8);
    #pragma unroll
    for (int i = 0; i < 4; ++i) {
      int s = i * 256 + w * 64 + lane;
      int srow = s & 255, skg = s >> 8;
      gload16(Bsb(r3) + i * 256 + w * 64,
              L2b + (size_t)(k * CS + srow) * HD + k0 + skg * 8);
    }
  };

  f32x4 acc[4][4] = {};
  STAGE(0, 0);
  STAGE(1, 1);
  asm volatile("s_waitcnt vmcnt(5)" ::: "memory");   // region 0 landed
  __builtin_amdgcn_s_barrier();

  for (int kk = 0; kk < HD / 32; ++kk) {  // 12 phases
    const int r3 = kk % 3;
    int4 af[4], bfr[4];
    #pragma unroll
    for (int mi = 0; mi < 4; ++mi) af[mi] = Asb(r3)[kg * 64 + mi * 16 + r];
    #pragma unroll
    for (int ni = 0; ni < 4; ++ni) bfr[ni] = Bsb(r3)[kg * 256 + w * 64 + ni * 16 + r];
    if (kk + 2 < HD / 32) STAGE((kk + 2) % 3, kk + 2);   // overwrites region read at kk-1
    __builtin_amdgcn_s_setprio(1);
    #pragma unroll
    for (int mi = 0; mi < 4; ++mi)
      #pragma unroll
      for (int ni = 0; ni < 4; ++ni)
        acc[mi][ni] = __builtin_amdgcn_mfma_f32_16x16x32_bf16(
            __builtin_bit_cast(bf16x8, af[mi]), __builtin_bit_cast(bf16x8, bfr[ni]),
            acc[mi][ni], 0, 0, 0);
    __builtin_amdgcn_s_setprio(0);
    if (kk + 1 < HD / 32) {
      if (kk + 2 < HD / 32) asm volatile("s_waitcnt vmcnt(5)" ::: "memory");
      else                  asm volatile("s_waitcnt vmcnt(0)" ::: "memory");
    }
    __builtin_amdgcn_s_barrier();
  }

  const int lr0 = (lane >> 4) * 4;
  #pragma unroll
  for (int mi = 0; mi < 4; ++mi)
    #pragma unroll
    for (int ni = 0; ni < 4; ++ni) {
      int col = w * 64 + ni * 16 + r;
      float bb = bias2p[k * CS + col];
      #pragma unroll
      for (int reg = 0; reg < 4; ++reg) {
        int row = mi * 16 + lr0 + reg;
        lg[row * 260 + col] = acc[mi][ni][reg] + bb;
      }
    }
  __syncthreads();

  int row = tid >> 2, part = tid & 3;
  const float4* rp = (const float4*)(lg + row * 260 + part * 64);
  float s = 0.f;
  #pragma unroll
  for (int i = 0; i < 16; ++i) {
    float4 v = rp[i];
    s += __expf(v.x) + __expf(v.y) + __expf(v.z) + __expf(v.w);
  }
  s += __shfl_xor(s, 1);
  s += __shfl_xor(s, 2);
  float contrib = 0.f;
  if (part == 0) {
    float lse = __logf(s);
    int c = ci[(size_t)(tm + row) * NCB + k];
    if (c >= 0) {
      c = c < CS ? c : CS - 1;
      contrib = lg[row * 260 + c] - lse;
    }
  }
  #pragma unroll
  for (int msk = 1; msk < 64; msk <<= 1) contrib += __shfl_xor(contrib, msk);
  if (lane == 0) red[w] = contrib;
  __syncthreads();
  if (tid == 0) atomicAdd(out, red[0] + red[1] + red[2] + red[3]);
}

extern "C" void kernel_launch(void* const* d_in, const int* in_sizes, int n_in,
                              void* d_out, int out_size, void* d_ws, size_t ws_size,
                              hipStream_t stream) {
  const float* predictor = (const float*)d_in[0];
  const int* cbidx       = (const int*)d_in[1];
  const float* W1        = (const float*)d_in[2];
  const float* b1        = (const float*)d_in[3];
  const float* lself     = (const float*)d_in[4];
  const float* gamma     = (const float*)d_in[5];
  const float* beta      = (const float*)d_in[6];
  const float* L2        = (const float*)d_in[7];
  const float* bias2     = (const float*)d_in[8];
  float* out = (float*)d_out;

  char* ws = (char*)d_ws;
  size_t off = 0;
  auto alloc = [&](size_t bytes) {
    char* p = ws + off;
    off += (bytes + 255) & ~(size_t)255;
    return p;
  };
  unsigned char* predB8  = (unsigned char*)alloc((size_t)NROW * PD);
  unsigned char* W1B8    = (unsigned char*)alloc((size_t)NH * PD);
  unsigned char* T       = (unsigned char*)alloc((size_t)LSC * LSR);
  unsigned short* Hb     = (unsigned short*)alloc((size_t)NROW * NH * 2);
  unsigned short* L2b    = (unsigned short*)alloc((size_t)NCB * CS * HD * 2);
  float* partials = (float*)alloc((size_t)2 * SA_NBLK * NH * 4);
  float* colsum = (float*)alloc(NH * 4);
  float* colsq  = (float*)alloc(NH * 4);
  float* scale  = (float*)alloc(NH * 4);
  float* shift  = (float*)alloc(NH * 4);
  float* bias2p = (float*)alloc(NCB * CS * 4);

  hipMemsetAsync(d_out, 0, 2 * sizeof(float), stream);
  hipMemsetAsync(colsum, 0, NH * 4, stream);
  hipMemsetAsync(colsq, 0, NH * 4, stream);

  k_f2b8<<<2048, 256, 0, stream>>>(predictor, (unsigned*)predB8, NROW * PD / 8);
  k_f2b8<<<2048, 256, 0, stream>>>(W1, (unsigned*)W1B8, NH * PD / 8);
  k_transpose<<<dim3(LSC / 32, LSR / 32), 256, 0, stream>>>(lself, T);
  k_count<<<NROW / 256, 256, 0, stream>>>(cbidx, out);
  k_gemm1<<<(NROW / 256) * (NH / 256), 512, 0, stream>>>(predB8, W1B8, b1, Hb);
  k_selfadd<<<dim3(3, SA_NBLK), 256, 0, stream>>>(Hb, T, cbidx, partials);
  k_red<<<dim3(NH / 256, 8), 256, 0, stream>>>(partials, colsum, colsq);
  k_bn<<<NH / 256, 256, 0, stream>>>(colsum, colsq, gamma, beta, scale, shift);
  k_fold<<<NCB * CS, 128, 0, stream>>>(L2, bias2, scale, shift, L2b, bias2p);
  k_passc<<<dim3(NROW / 64, NCB), 256, 0, stream>>>(Hb, L2b, bias2p, cbidx, out);
}

// Round 17
// 733.451 us; speedup vs baseline: 1.5731x; 1.1670x over previous
//
#include <hip/hip_runtime.h>
#include <hip/hip_bf16.h>

#define NCB 16
#define CS 256
#define HD 384
#define PD 2048
#define NROW 16384
#define NH 6144      // NCB*HD
#define LSR 5760     // (NCB-1)*HD  rows of linear_self
#define LSC 3840     // (NCB-1)*CS  cols of linear_self
#define SA_ROWS 32
#define SA_NBLK (NROW / SA_ROWS)   // 512
#define GNT (PD / 128)             // 16 K-tiles for fp8 gemm1 (BK=128)

typedef __bf16 bf16x8 __attribute__((ext_vector_type(8)));
typedef float f32x4 __attribute__((ext_vector_type(4)));
typedef int int4v __attribute__((ext_vector_type(4)));
typedef int int2v __attribute__((ext_vector_type(2)));

__device__ __forceinline__ unsigned short f2bf(float f) {
  unsigned u = __builtin_bit_cast(unsigned, f);
  u = (u + 0x7fffu + ((u >> 16) & 1u)) >> 16;
  return (unsigned short)u;
}
__device__ __forceinline__ float bf2f(unsigned short h) {
  unsigned u = ((unsigned)h) << 16;
  return __builtin_bit_cast(float, u);
}
__device__ __forceinline__ unsigned char f2fp8(float f) {
  return (unsigned char)__builtin_amdgcn_cvt_pk_fp8_f32(f, f, 0, false);
}

__device__ __forceinline__ void gload16(void* lds, const void* g) {
  __builtin_amdgcn_global_load_lds(
      (const __attribute__((address_space(1))) unsigned int*)g,
      (__attribute__((address_space(3))) unsigned int*)lds, 16, 0, 0);
}

// ---------------- fp32 -> fp8 e4m3 conversion (8 elements/thread/iter) ----------------
__global__ void k_f2b8(const float* __restrict__ in, unsigned* __restrict__ out, int n8) {
  for (int i = blockIdx.x * 256 + threadIdx.x; i < n8; i += gridDim.x * 256) {
    float4 a = ((const float4*)in)[i * 2];
    float4 b = ((const float4*)in)[i * 2 + 1];
    unsigned lo = __builtin_amdgcn_cvt_pk_fp8_f32(a.x, a.y, 0, false);
    lo = __builtin_amdgcn_cvt_pk_fp8_f32(a.z, a.w, lo, true);
    unsigned hi = __builtin_amdgcn_cvt_pk_fp8_f32(b.x, b.y, 0, false);
    hi = __builtin_amdgcn_cvt_pk_fp8_f32(b.z, b.w, hi, true);
    uint2 o = {lo, hi};
    ((uint2*)out)[i] = o;
  }
}

// ---------------- transpose linear_self (5760x3840 f32) -> T (3840x5760 fp8 e4m3) ----------------
__global__ __launch_bounds__(256) void k_transpose(const float* __restrict__ LS,
                                                   unsigned char* __restrict__ T) {
  __shared__ float tile[32][33];
  int tx = threadIdx.x & 31, ty = threadIdx.x >> 5;
  int c0 = blockIdx.x * 32;  // col of LS = row of T
  int r0 = blockIdx.y * 32;  // row of LS = col of T
  for (int i = ty; i < 32; i += 8)
    tile[i][tx] = LS[(size_t)(r0 + i) * LSC + c0 + tx];
  __syncthreads();
  const int i = threadIdx.x >> 3;        // T-row offset 0..31
  const int q = (threadIdx.x & 7) * 4;   // r-offset 0,4,..,28
  unsigned u = __builtin_amdgcn_cvt_pk_fp8_f32(tile[q][i], tile[q + 1][i], 0, false);
  u = __builtin_amdgcn_cvt_pk_fp8_f32(tile[q + 2][i], tile[q + 3][i], u, true);
  *(unsigned*)(T + (size_t)(c0 + i) * LSR + r0 + q) = u;
}

// ---------------- count valid[:,0] ----------------
__global__ void k_count(const int* __restrict__ ci, float* __restrict__ out) {
  int n = blockIdx.x * 256 + threadIdx.x;
  float v = (n < NROW && ci[(size_t)n * NCB] >= 0) ? 1.f : 0.f;
  #pragma unroll
  for (int m = 1; m < 64; m <<= 1) v += __shfl_xor(v, m);
  if ((threadIdx.x & 63) == 0) atomicAdd(out + 1, v);
}

// ---------------- GEMM1 (fp8): 256x256 tile, BK=128 (2 k-halves of 64), 8 waves ----------------
// r15 frozen core; epilogue stores fp8 H (halves H write traffic).
__global__ __launch_bounds__(512, 2) void k_gemm1(
    const unsigned char* __restrict__ A,   // predictor fp8 [NROW][PD]
    const unsigned char* __restrict__ B,   // W1 fp8 [NH][PD]
    const float* __restrict__ b1,
    unsigned char* __restrict__ H) {       // out [NROW][NH] fp8 (pre-activation)
  __shared__ int4v Al[2][2][1024];   // [buf][kh][row*4+pc] 16B granules (64 KB)
  __shared__ int4v Bl[2][2][1024];

  const int tid = threadIdx.x;
  const int lane = tid & 63;
  const int w = tid >> 6;             // 0..7
  const int wr = w >> 2, wc = w & 3;  // wave grid 2(M) x 4(N)
  const int l15 = lane & 15, hi = lane >> 4;
  const int w64 = tid & ~63;

  // XCD swizzle: grid 1536 = 64 mt x 24 nt; each XCD owns 3 nt
  const int bid = blockIdx.x;
  const int xcd = bid & 7, p = bid >> 3;   // p in [0,192)
  const int nt = xcd * 3 + p % 3;
  const int mt = p / 3;
  const int tm = mt * 256, tn = nt * 256;

  f32x4 acc[8][4] = {};

  auto STAGE = [&](int buf, int t, int kh) {
    const int kb = t * 128 + kh * 64;   // byte offset along K
    #pragma unroll
    for (int g = 0; g < 2; ++g) {
      const int slot = g * 512 + tid;
      const int row = slot >> 2;                       // 0..255
      const int lc = (slot & 3) ^ ((row >> 1) & 3);    // inverse-swizzled source granule
      gload16(&Al[buf][kh][g * 512 + w64], A + (size_t)(tm + row) * PD + kb + lc * 16);
      gload16(&Bl[buf][kh][g * 512 + w64], B + (size_t)(tn + row) * PD + kb + lc * 16);
    }
  };

  // prologue: t0.kh0, t0.kh1, t1.kh0 -> 12 loads; wait oldest 4 (t0.kh0)
  STAGE(0, 0, 0);
  STAGE(0, 0, 1);
  STAGE(1, 1, 0);
  asm volatile("s_waitcnt vmcnt(8)" ::: "memory");
  __builtin_amdgcn_s_barrier();

  for (int t = 0; t < GNT; ++t) {
    const int buf = t & 1;
    #pragma unroll
    for (int kh = 0; kh < 2; ++kh) {
      // frag reads (swizzled, b128 each = K=64 of fp8)
      int4v af[8], bfr[4];
      #pragma unroll
      for (int mi = 0; mi < 8; ++mi) {
        const int row = wr * 128 + mi * 16 + l15;
        const int pc = hi ^ ((row >> 1) & 3);
        af[mi] = Al[buf][kh][row * 4 + pc];
      }
      #pragma unroll
      for (int ni = 0; ni < 4; ++ni) {
        const int row = wc * 64 + ni * 16 + l15;
        const int pc = hi ^ ((row >> 1) & 3);
        bfr[ni] = Bl[buf][kh][row * 4 + pc];
      }
      // stage prefetch (regions race-safe, r7/r11 audit)
      if (kh == 0) {
        if (t + 1 < GNT) STAGE(buf ^ 1, t + 1, 1);
      } else {
        if (t + 2 < GNT) STAGE(buf, t + 2, 0);
      }
      // (barrier #1 removed — cross-wave LDS/VALU vs MFMA overlap)
      __builtin_amdgcn_s_setprio(1);
      #pragma unroll
      for (int mi = 0; mi < 8; ++mi) {
        int2v alo_, ahi_;
        alo_[0] = af[mi][0]; alo_[1] = af[mi][1];
        ahi_[0] = af[mi][2]; ahi_[1] = af[mi][3];
        const long a1 = __builtin_bit_cast(long, alo_);
        const long a2 = __builtin_bit_cast(long, ahi_);
        #pragma unroll
        for (int ni = 0; ni < 4; ++ni) {
          int2v blo_, bhi_;
          blo_[0] = bfr[ni][0]; blo_[1] = bfr[ni][1];
          bhi_[0] = bfr[ni][2]; bhi_[1] = bfr[ni][3];
          acc[mi][ni] = __builtin_amdgcn_mfma_f32_16x16x32_fp8_fp8(
              a1, __builtin_bit_cast(long, blo_), acc[mi][ni], 0, 0, 0);
          acc[mi][ni] = __builtin_amdgcn_mfma_f32_16x16x32_fp8_fp8(
              a2, __builtin_bit_cast(long, bhi_), acc[mi][ni], 0, 0, 0);
        }
      }
      __builtin_amdgcn_s_setprio(0);
      // counted drains (audited): A-phase needs t.kh1; B-phase needs (t+1).kh0
      if (kh == 0) {
        if (t < GNT - 1) asm volatile("s_waitcnt vmcnt(8)" ::: "memory");
        else             asm volatile("s_waitcnt vmcnt(0)" ::: "memory");
      } else {
        if (t < GNT - 2)      asm volatile("s_waitcnt vmcnt(8)" ::: "memory");
        else if (t == GNT - 2) asm volatile("s_waitcnt vmcnt(4)" ::: "memory");
      }
      __builtin_amdgcn_s_barrier();
    }
  }

  // epilogue: bias + fp8 NT store (pre-activation)
  #pragma unroll
  for (int ni = 0; ni < 4; ++ni) {
    const int col = tn + wc * 64 + ni * 16 + l15;
    const float bb = b1[col];
    #pragma unroll
    for (int mi = 0; mi < 8; ++mi)
      #pragma unroll
      for (int reg = 0; reg < 4; ++reg) {
        const int row = tm + wr * 128 + mi * 16 + hi * 4 + reg;
        __builtin_nontemporal_store(f2fp8(acc[mi][ni][reg] + bb),
                                    H + (size_t)row * NH + col);
      }
  }
}

// ---------------- self-pred gather: branch-free unrolled, fp8 T + fp8 H ----------------
template <int KM>
__device__ __forceinline__ void gather_chunk(
    const unsigned char* __restrict__ T, const int* idxrow,
    int oo, int bbv, float v[8]) {
  #pragma unroll
  for (int kc = 0; kc < KM; ++kc) {
    int c = idxrow[kc];
    float m = (c >= 0 && kc <= bbv) ? 1.f : 0.f;
    int cc = c < 0 ? 0 : (c >= CS ? CS - 1 : c);
    int2 tv = *(const int2*)(T + (size_t)(kc * CS + cc) * LSR + oo);  // 8 fp8
    float f[8];
    f[0] = __builtin_amdgcn_cvt_f32_fp8(tv.x, 0);
    f[1] = __builtin_amdgcn_cvt_f32_fp8(tv.x, 1);
    f[2] = __builtin_amdgcn_cvt_f32_fp8(tv.x, 2);
    f[3] = __builtin_amdgcn_cvt_f32_fp8(tv.x, 3);
    f[4] = __builtin_amdgcn_cvt_f32_fp8(tv.y, 0);
    f[5] = __builtin_amdgcn_cvt_f32_fp8(tv.y, 1);
    f[6] = __builtin_amdgcn_cvt_f32_fp8(tv.y, 2);
    f[7] = __builtin_amdgcn_cvt_f32_fp8(tv.y, 3);
    #pragma unroll
    for (int e = 0; e < 8; ++e) v[e] = fmaf(m, f[e], v[e]);
  }
}

// grid = dim3(3, SA_NBLK): x = 2048-col stripe, y = 32-row block.
// H is fp8 in-place: read pre-act fp8, add self_pred, relu, store fp8 + stats.
__global__ __launch_bounds__(256) void k_selfadd(
    unsigned char* __restrict__ H,         // [NROW][NH] fp8, in-place
    const unsigned char* __restrict__ T,   // [LSC][LSR] fp8 (linear_self^T)
    const int* __restrict__ ci,
    float* __restrict__ partials) {        // [2][SA_NBLK][NH]
  __shared__ int idxs[SA_ROWS][NCB];
  const int tid = threadIdx.x;
  const int row0 = blockIdx.y * SA_ROWS;
  const int sx = blockIdx.x;               // 0..2, block-uniform
  for (int i = tid; i < SA_ROWS * NCB; i += 256)
    idxs[i >> 4][i & 15] = ci[(size_t)(row0 + (i >> 4)) * NCB + (i & 15)];
  __syncthreads();

  const int col0 = sx * 2048 + tid * 8;
  const int o = col0 - HD;
  const int oo = o < 0 ? 0 : o;
  const int bb = o < 0 ? -1 : o / HD;

  float cs[8] = {0}, cq[8] = {0};

  for (int rr = 0; rr < SA_ROWS; ++rr) {
    const size_t ro = (size_t)(row0 + rr) * NH;
    int2v hv = __builtin_nontemporal_load((const int2v*)(H + ro + col0));
    float v[8];
    v[0] = __builtin_amdgcn_cvt_f32_fp8(hv[0], 0);
    v[1] = __builtin_amdgcn_cvt_f32_fp8(hv[0], 1);
    v[2] = __builtin_amdgcn_cvt_f32_fp8(hv[0], 2);
    v[3] = __builtin_amdgcn_cvt_f32_fp8(hv[0], 3);
    v[4] = __builtin_amdgcn_cvt_f32_fp8(hv[1], 0);
    v[5] = __builtin_amdgcn_cvt_f32_fp8(hv[1], 1);
    v[6] = __builtin_amdgcn_cvt_f32_fp8(hv[1], 2);
    v[7] = __builtin_amdgcn_cvt_f32_fp8(hv[1], 3);
    switch (sx) {  // block-uniform branch, compile-time gather depth
      case 0: gather_chunk<5>(T, idxs[rr], oo, bb, v); break;
      case 1: gather_chunk<10>(T, idxs[rr], oo, bb, v); break;
      default: gather_chunk<15>(T, idxs[rr], oo, bb, v); break;
    }
    float x[8];
    #pragma unroll
    for (int e = 0; e < 8; ++e) x[e] = fmaxf(v[e], 0.f);
    int2v ov;
    unsigned w0 = __builtin_amdgcn_cvt_pk_fp8_f32(x[0], x[1], 0, false);
    w0 = __builtin_amdgcn_cvt_pk_fp8_f32(x[2], x[3], w0, true);
    unsigned w1 = __builtin_amdgcn_cvt_pk_fp8_f32(x[4], x[5], 0, false);
    w1 = __builtin_amdgcn_cvt_pk_fp8_f32(x[6], x[7], w1, true);
    ov[0] = (int)w0; ov[1] = (int)w1;
    // stats from the fp8-rounded stored value (self-consistent with passc);
    // literal selectors required by the builtin
    float xr0 = __builtin_amdgcn_cvt_f32_fp8(w0, 0);
    float xr1 = __builtin_amdgcn_cvt_f32_fp8(w0, 1);
    float xr2 = __builtin_amdgcn_cvt_f32_fp8(w0, 2);
    float xr3 = __builtin_amdgcn_cvt_f32_fp8(w0, 3);
    float xr4 = __builtin_amdgcn_cvt_f32_fp8(w1, 0);
    float xr5 = __builtin_amdgcn_cvt_f32_fp8(w1, 1);
    float xr6 = __builtin_amdgcn_cvt_f32_fp8(w1, 2);
    float xr7 = __builtin_amdgcn_cvt_f32_fp8(w1, 3);
    cs[0] += xr0; cq[0] += xr0 * xr0;
    cs[1] += xr1; cq[1] += xr1 * xr1;
    cs[2] += xr2; cq[2] += xr2 * xr2;
    cs[3] += xr3; cq[3] += xr3 * xr3;
    cs[4] += xr4; cq[4] += xr4 * xr4;
    cs[5] += xr5; cq[5] += xr5 * xr5;
    cs[6] += xr6; cq[6] += xr6 * xr6;
    cs[7] += xr7; cq[7] += xr7 * xr7;
    __builtin_nontemporal_store(ov, (int2v*)(H + ro + col0));
  }

  float* Ps = partials + (size_t)blockIdx.y * NH + col0;
  float* Pq = partials + (size_t)(SA_NBLK + blockIdx.y) * NH + col0;
  float4 a = {cs[0], cs[1], cs[2], cs[3]};
  float4 b4 = {cs[4], cs[5], cs[6], cs[7]};
  *(float4*)Ps = a; *(float4*)(Ps + 4) = b4;
  float4 c4 = {cq[0], cq[1], cq[2], cq[3]};
  float4 d4 = {cq[4], cq[5], cq[6], cq[7]};
  *(float4*)Pq = c4; *(float4*)(Pq + 4) = d4;
}

// ---------------- reduce partials -> colsum/colsq ----------------
// grid dim3(NH/256, 8)
__global__ void k_red(const float* __restrict__ partials,
                      float* __restrict__ colsum, float* __restrict__ colsq) {
  int j = blockIdx.x * 256 + threadIdx.x;
  const float* Ps = partials;
  const float* Pq = partials + (size_t)SA_NBLK * NH;
  float s = 0.f, q = 0.f;
  const int b0 = blockIdx.y * (SA_NBLK / 8), b1 = b0 + SA_NBLK / 8;
  for (int by = b0; by < b1; ++by) {
    s += Ps[(size_t)by * NH + j];
    q += Pq[(size_t)by * NH + j];
  }
  atomicAdd(colsum + j, s);
  atomicAdd(colsq + j, q);
}

// ---------------- BN params ----------------
__global__ void k_bn(const float* __restrict__ colsum, const float* __restrict__ colsq,
                     const float* __restrict__ gamma, const float* __restrict__ beta,
                     float* __restrict__ scale, float* __restrict__ shift) {
  int j = blockIdx.x * 256 + threadIdx.x;
  if (j >= NH) return;
  float mean = colsum[j] * (1.f / NROW);
  float var = colsq[j] * (1.f / NROW) - mean * mean;
  var = fmaxf(var, 0.f);
  float rs = rsqrtf(var + 1e-5f);
  float g = gamma[j] * rs;
  scale[j] = g;
  shift[j] = beta[j] - mean * g;
}

// ---------------- fold BN into linear2/bias2 (fp8 L2b) ----------------
__global__ __launch_bounds__(128) void k_fold(
    const float* __restrict__ L2, const float* __restrict__ bias2,
    const float* __restrict__ scale, const float* __restrict__ shift,
    unsigned char* __restrict__ L2b8, float* __restrict__ bias2p) {
  __shared__ float red[2];
  int kc = blockIdx.x;        // k*256 + c
  int k = kc >> 8;
  size_t off = (size_t)kc * HD;
  float a = 0.f;
  for (int h = threadIdx.x; h < HD; h += 128) {
    float wv = L2[off + h];
    int jh = k * HD + h;
    L2b8[off + h] = f2fp8(wv * scale[jh]);
    a += wv * shift[jh];
  }
  #pragma unroll
  for (int m = 1; m < 64; m <<= 1) a += __shfl_xor(a, m);
  if ((threadIdx.x & 63) == 0) red[threadIdx.x >> 6] = a;
  __syncthreads();
  if (threadIdx.x == 0) bias2p[kc] = bias2[kc] + red[0] + red[1];
}

// ---------------- pass C (fp8): logits GEMM + log-softmax + target gather ----------------
// grid dim3(256,16); XCD swizzle (2 codebooks/XCD). fp8 H and L2b: 6 phases of
// K=64 (dual-MFMA per frag, gemm1's K-permutation trick), 3-region counted vmcnt(5).
__global__ __launch_bounds__(256, 2) void k_passc(
    const unsigned char* __restrict__ H,      // [NROW][NH] fp8
    const unsigned char* __restrict__ L2b8,   // [NCB][CS][HD] fp8 (BN-folded)
    const float* __restrict__ bias2p,         // [NCB][CS]
    const int* __restrict__ ci,
    float* __restrict__ out) {
  __shared__ char smem[64 * 260 * 4];  // 66560B; 3x20480 staging aliased under lg
  __shared__ float red[4];
  float* lg = (float*)smem;            // [64][260]

  const int tid = threadIdx.x, lane = tid & 63, w = tid >> 6;
  const int bidf = blockIdx.y * gridDim.x + blockIdx.x;  // 0..4095
  const int xcd = bidf & 7, p = bidf >> 3;               // p in [0,512)
  const int k = xcd * 2 + (p & 1);
  const int tm = (p >> 1) * 64;
  const int r = lane & 15, hi = lane >> 4;
  const int w64 = tid & ~63;

  auto Asb = [&](int r3) { return (int4v*)(smem + r3 * 20480); };           // 4KB: [64 rows][4 granules]
  auto Bsb = [&](int r3) { return (int4v*)(smem + r3 * 20480 + 4096); };    // 16KB: [256 rows][4 granules]

  auto STAGE = [&](int r3, int kk) {
    const int kb = kk * 64;     // fp8 bytes along K
    {
      const int row = tid >> 2;
      const int pc = (tid & 3) ^ ((row >> 1) & 3);
      gload16(Asb(r3) + w64, H + (size_t)(tm + row) * NH + k * HD + kb + pc * 16);
    }
    #pragma unroll
    for (int i = 0; i < 4; ++i) {
      const int slot = i * 256 + tid;
      const int row = slot >> 2;
      const int pc = (slot & 3) ^ ((row >> 1) & 3);
      gload16(Bsb(r3) + i * 256 + w64,
              L2b8 + (size_t)(k * CS + row) * HD + kb + pc * 16);
    }
  };

  f32x4 acc[4][4] = {};
  STAGE(0, 0);
  STAGE(1, 1);
  asm volatile("s_waitcnt vmcnt(5)" ::: "memory");   // region 0 landed
  __builtin_amdgcn_s_barrier();

  for (int kk = 0; kk < HD / 64; ++kk) {  // 6 phases
    const int r3 = kk % 3;
    int4v af[4], bfr[4];
    #pragma unroll
    for (int mi = 0; mi < 4; ++mi) {
      const int row = mi * 16 + r;
      af[mi] = Asb(r3)[row * 4 + (hi ^ ((row >> 1) & 3))];
    }
    #pragma unroll
    for (int ni = 0; ni < 4; ++ni) {
      const int row = w * 64 + ni * 16 + r;
      bfr[ni] = Bsb(r3)[row * 4 + (hi ^ ((row >> 1) & 3))];
    }
    if (kk + 2 < HD / 64) STAGE((kk + 2) % 3, kk + 2);
    __builtin_amdgcn_s_setprio(1);
    #pragma unroll
    for (int mi = 0; mi < 4; ++mi) {
      int2v alo_, ahi_;
      alo_[0] = af[mi][0]; alo_[1] = af[mi][1];
      ahi_[0] = af[mi][2]; ahi_[1] = af[mi][3];
      const long a1 = __builtin_bit_cast(long, alo_);
      const long a2 = __builtin_bit_cast(long, ahi_);
      #pragma unroll
      for (int ni = 0; ni < 4; ++ni) {
        int2v blo_, bhi_;
        blo_[0] = bfr[ni][0]; blo_[1] = bfr[ni][1];
        bhi_[0] = bfr[ni][2]; bhi_[1] = bfr[ni][3];
        acc[mi][ni] = __builtin_amdgcn_mfma_f32_16x16x32_fp8_fp8(
            a1, __builtin_bit_cast(long, blo_), acc[mi][ni], 0, 0, 0);
        acc[mi][ni] = __builtin_amdgcn_mfma_f32_16x16x32_fp8_fp8(
            a2, __builtin_bit_cast(long, bhi_), acc[mi][ni], 0, 0, 0);
      }
    }
    __builtin_amdgcn_s_setprio(0);
    if (kk + 1 < HD / 64) {
      if (kk + 2 < HD / 64) asm volatile("s_waitcnt vmcnt(5)" ::: "memory");
      else                  asm volatile("s_waitcnt vmcnt(0)" ::: "memory");
    }
    __builtin_amdgcn_s_barrier();
  }

  const int lr0 = hi * 4;
  #pragma unroll
  for (int mi = 0; mi < 4; ++mi)
    #pragma unroll
    for (int ni = 0; ni < 4; ++ni) {
      int col = w * 64 + ni * 16 + r;
      float bb = bias2p[k * CS + col];
      #pragma unroll
      for (int reg = 0; reg < 4; ++reg) {
        int row = mi * 16 + lr0 + reg;
        lg[row * 260 + col] = acc[mi][ni][reg] + bb;
      }
    }
  __syncthreads();

  int row = tid >> 2, part = tid & 3;
  const float4* rp = (const float4*)(lg + row * 260 + part * 64);
  float s = 0.f;
  #pragma unroll
  for (int i = 0; i < 16; ++i) {
    float4 v = rp[i];
    s += __expf(v.x) + __expf(v.y) + __expf(v.z) + __expf(v.w);
  }
  s += __shfl_xor(s, 1);
  s += __shfl_xor(s, 2);
  float contrib = 0.f;
  if (part == 0) {
    float lse = __logf(s);
    int c = ci[(size_t)(tm + row) * NCB + k];
    if (c >= 0) {
      c = c < CS ? c : CS - 1;
      contrib = lg[row * 260 + c] - lse;
    }
  }
  #pragma unroll
  for (int msk = 1; msk < 64; msk <<= 1) contrib += __shfl_xor(contrib, msk);
  if (lane == 0) red[w] = contrib;
  __syncthreads();
  if (tid == 0) atomicAdd(out, red[0] + red[1] + red[2] + red[3]);
}

extern "C" void kernel_launch(void* const* d_in, const int* in_sizes, int n_in,
                              void* d_out, int out_size, void* d_ws, size_t ws_size,
                              hipStream_t stream) {
  const float* predictor = (const float*)d_in[0];
  const int* cbidx       = (const int*)d_in[1];
  const float* W1        = (const float*)d_in[2];
  const float* b1        = (const float*)d_in[3];
  const float* lself     = (const float*)d_in[4];
  const float* gamma     = (const float*)d_in[5];
  const float* beta      = (const float*)d_in[6];
  const float* L2        = (const float*)d_in[7];
  const float* bias2     = (const float*)d_in[8];
  float* out = (float*)d_out;

  char* ws = (char*)d_ws;
  size_t off = 0;
  auto alloc = [&](size_t bytes) {
    char* p = ws + off;
    off += (bytes + 255) & ~(size_t)255;
    return p;
  };
  unsigned char* predB8  = (unsigned char*)alloc((size_t)NROW * PD);
  unsigned char* W1B8    = (unsigned char*)alloc((size_t)NH * PD);
  unsigned char* T       = (unsigned char*)alloc((size_t)LSC * LSR);
  unsigned char* H8      = (unsigned char*)alloc((size_t)NROW * NH);
  unsigned char* L2b8    = (unsigned char*)alloc((size_t)NCB * CS * HD);
  float* partials = (float*)alloc((size_t)2 * SA_NBLK * NH * 4);
  float* colsum = (float*)alloc(NH * 4);
  float* colsq  = (float*)alloc(NH * 4);
  float* scale  = (float*)alloc(NH * 4);
  float* shift  = (float*)alloc(NH * 4);
  float* bias2p = (float*)alloc(NCB * CS * 4);

  hipMemsetAsync(d_out, 0, 2 * sizeof(float), stream);
  hipMemsetAsync(colsum, 0, NH * 4, stream);
  hipMemsetAsync(colsq, 0, NH * 4, stream);

  k_f2b8<<<2048, 256, 0, stream>>>(predictor, (unsigned*)predB8, NROW * PD / 8);
  k_f2b8<<<2048, 256, 0, stream>>>(W1, (unsigned*)W1B8, NH * PD / 8);
  k_transpose<<<dim3(LSC / 32, LSR / 32), 256, 0, stream>>>(lself, T);
  k_count<<<NROW / 256, 256, 0, stream>>>(cbidx, out);
  k_gemm1<<<(NROW / 256) * (NH / 256), 512, 0, stream>>>(predB8, W1B8, b1, H8);
  k_selfadd<<<dim3(3, SA_NBLK), 256, 0, stream>>>(H8, T, cbidx, partials);
  k_red<<<dim3(NH / 256, 8), 256, 0, stream>>>(partials, colsum, colsq);
  k_bn<<<NH / 256, 256, 0, stream>>>(colsum, colsq, gamma, beta, scale, shift);
  k_fold<<<NCB * CS, 128, 0, stream>>>(L2, bias2, scale, shift, L2b8, bias2p);
  k_passc<<<dim3(NROW / 64, NCB), 256, 0, stream>>>(H8, L2b8, bias2p, cbidx, out);
}

// Round 18
// 731.755 us; speedup vs baseline: 1.5768x; 1.0023x over previous
//
#include <hip/hip_runtime.h>
#include <hip/hip_bf16.h>

#define NCB 16
#define CS 256
#define HD 384
#define PD 2048
#define NROW 16384
#define NH 6144      // NCB*HD
#define LSR 5760     // (NCB-1)*HD  rows of linear_self
#define LSC 3840     // (NCB-1)*CS  cols of linear_self
#define SA_ROWS 32
#define SA_NBLK (NROW / SA_ROWS)   // 512
#define GNT (PD / 128)             // 16 K-tiles for fp8 gemm1 (BK=128)

typedef __bf16 bf16x8 __attribute__((ext_vector_type(8)));
typedef float f32x4 __attribute__((ext_vector_type(4)));
typedef int int4v __attribute__((ext_vector_type(4)));
typedef int int2v __attribute__((ext_vector_type(2)));

__device__ __forceinline__ unsigned short f2bf(float f) {
  unsigned u = __builtin_bit_cast(unsigned, f);
  u = (u + 0x7fffu + ((u >> 16) & 1u)) >> 16;
  return (unsigned short)u;
}
__device__ __forceinline__ float bf2f(unsigned short h) {
  unsigned u = ((unsigned)h) << 16;
  return __builtin_bit_cast(float, u);
}
__device__ __forceinline__ unsigned char f2fp8(float f) {
  return (unsigned char)__builtin_amdgcn_cvt_pk_fp8_f32(f, f, 0, false);
}
__device__ __forceinline__ long lo64(int4v v) {
  int2v t; t[0] = v[0]; t[1] = v[1];
  return __builtin_bit_cast(long, t);
}
__device__ __forceinline__ long hi64(int4v v) {
  int2v t; t[0] = v[2]; t[1] = v[3];
  return __builtin_bit_cast(long, t);
}

__device__ __forceinline__ void gload16(void* lds, const void* g) {
  __builtin_amdgcn_global_load_lds(
      (const __attribute__((address_space(1))) unsigned int*)g,
      (__attribute__((address_space(3))) unsigned int*)lds, 16, 0, 0);
}

// ---------------- fp32 -> fp8 e4m3 conversion (8 elements/thread/iter) ----------------
__global__ void k_f2b8(const float* __restrict__ in, unsigned* __restrict__ out, int n8) {
  for (int i = blockIdx.x * 256 + threadIdx.x; i < n8; i += gridDim.x * 256) {
    float4 a = ((const float4*)in)[i * 2];
    float4 b = ((const float4*)in)[i * 2 + 1];
    unsigned lo = __builtin_amdgcn_cvt_pk_fp8_f32(a.x, a.y, 0, false);
    lo = __builtin_amdgcn_cvt_pk_fp8_f32(a.z, a.w, lo, true);
    unsigned hi = __builtin_amdgcn_cvt_pk_fp8_f32(b.x, b.y, 0, false);
    hi = __builtin_amdgcn_cvt_pk_fp8_f32(b.z, b.w, hi, true);
    uint2 o = {lo, hi};
    ((uint2*)out)[i] = o;
  }
}

// ---------------- transpose linear_self (5760x3840 f32) -> T (3840x5760 fp8 e4m3) ----------------
__global__ __launch_bounds__(256) void k_transpose(const float* __restrict__ LS,
                                                   unsigned char* __restrict__ T) {
  __shared__ float tile[32][33];
  int tx = threadIdx.x & 31, ty = threadIdx.x >> 5;
  int c0 = blockIdx.x * 32;  // col of LS = row of T
  int r0 = blockIdx.y * 32;  // row of LS = col of T
  for (int i = ty; i < 32; i += 8)
    tile[i][tx] = LS[(size_t)(r0 + i) * LSC + c0 + tx];
  __syncthreads();
  const int i = threadIdx.x >> 3;        // T-row offset 0..31
  const int q = (threadIdx.x & 7) * 4;   // r-offset 0,4,..,28
  unsigned u = __builtin_amdgcn_cvt_pk_fp8_f32(tile[q][i], tile[q + 1][i], 0, false);
  u = __builtin_amdgcn_cvt_pk_fp8_f32(tile[q + 2][i], tile[q + 3][i], u, true);
  *(unsigned*)(T + (size_t)(c0 + i) * LSR + r0 + q) = u;
}

// ---------------- count valid[:,0] ----------------
__global__ void k_count(const int* __restrict__ ci, float* __restrict__ out) {
  int n = blockIdx.x * 256 + threadIdx.x;
  float v = (n < NROW && ci[(size_t)n * NCB] >= 0) ? 1.f : 0.f;
  #pragma unroll
  for (int m = 1; m < 64; m <<= 1) v += __shfl_xor(v, m);
  if ((threadIdx.x & 63) == 0) atomicAdd(out + 1, v);
}

// ---------------- GEMM1 (fp8): 256x256 tile, BK=128 (2 k-halves of 64), 8 waves ----------------
// r17 core + MFMA dependency fix: K-half loop hoisted outermost so consecutive
// MFMAs hit distinct accumulators (dep distance 32 instrs, not 1).
__global__ __launch_bounds__(512, 2) void k_gemm1(
    const unsigned char* __restrict__ A,   // predictor fp8 [NROW][PD]
    const unsigned char* __restrict__ B,   // W1 fp8 [NH][PD]
    const float* __restrict__ b1,
    unsigned char* __restrict__ H) {       // out [NROW][NH] fp8 (pre-activation)
  __shared__ int4v Al[2][2][1024];   // [buf][kh][row*4+pc] 16B granules (64 KB)
  __shared__ int4v Bl[2][2][1024];

  const int tid = threadIdx.x;
  const int lane = tid & 63;
  const int w = tid >> 6;             // 0..7
  const int wr = w >> 2, wc = w & 3;  // wave grid 2(M) x 4(N)
  const int l15 = lane & 15, hi = lane >> 4;
  const int w64 = tid & ~63;

  // XCD swizzle: grid 1536 = 64 mt x 24 nt; each XCD owns 3 nt
  const int bid = blockIdx.x;
  const int xcd = bid & 7, p = bid >> 3;   // p in [0,192)
  const int nt = xcd * 3 + p % 3;
  const int mt = p / 3;
  const int tm = mt * 256, tn = nt * 256;

  f32x4 acc[8][4] = {};

  auto STAGE = [&](int buf, int t, int kh) {
    const int kb = t * 128 + kh * 64;   // byte offset along K
    #pragma unroll
    for (int g = 0; g < 2; ++g) {
      const int slot = g * 512 + tid;
      const int row = slot >> 2;                       // 0..255
      const int lc = (slot & 3) ^ ((row >> 1) & 3);    // inverse-swizzled source granule
      gload16(&Al[buf][kh][g * 512 + w64], A + (size_t)(tm + row) * PD + kb + lc * 16);
      gload16(&Bl[buf][kh][g * 512 + w64], B + (size_t)(tn + row) * PD + kb + lc * 16);
    }
  };

  // prologue: t0.kh0, t0.kh1, t1.kh0 -> 12 loads; wait oldest 4 (t0.kh0)
  STAGE(0, 0, 0);
  STAGE(0, 0, 1);
  STAGE(1, 1, 0);
  asm volatile("s_waitcnt vmcnt(8)" ::: "memory");
  __builtin_amdgcn_s_barrier();

  for (int t = 0; t < GNT; ++t) {
    const int buf = t & 1;
    #pragma unroll
    for (int kh = 0; kh < 2; ++kh) {
      // frag reads (swizzled, b128 each = K=64 of fp8)
      int4v af[8], bfr[4];
      #pragma unroll
      for (int mi = 0; mi < 8; ++mi) {
        const int row = wr * 128 + mi * 16 + l15;
        const int pc = hi ^ ((row >> 1) & 3);
        af[mi] = Al[buf][kh][row * 4 + pc];
      }
      #pragma unroll
      for (int ni = 0; ni < 4; ++ni) {
        const int row = wc * 64 + ni * 16 + l15;
        const int pc = hi ^ ((row >> 1) & 3);
        bfr[ni] = Bl[buf][kh][row * 4 + pc];
      }
      // stage prefetch (regions race-safe, r7/r11 audit)
      if (kh == 0) {
        if (t + 1 < GNT) STAGE(buf ^ 1, t + 1, 1);
      } else {
        if (t + 2 < GNT) STAGE(buf, t + 2, 0);
      }
      // (barrier #1 removed — cross-wave LDS/VALU vs MFMA overlap)
      __builtin_amdgcn_s_setprio(1);
      // K-half 0: 32 independent MFMAs (distinct acc regs)
      #pragma unroll
      for (int mi = 0; mi < 8; ++mi) {
        const long a1 = lo64(af[mi]);
        #pragma unroll
        for (int ni = 0; ni < 4; ++ni)
          acc[mi][ni] = __builtin_amdgcn_mfma_f32_16x16x32_fp8_fp8(
              a1, lo64(bfr[ni]), acc[mi][ni], 0, 0, 0);
      }
      // K-half 1: 32 independent MFMAs (dep distance to half-0 = 32 instrs)
      #pragma unroll
      for (int mi = 0; mi < 8; ++mi) {
        const long a2 = hi64(af[mi]);
        #pragma unroll
        for (int ni = 0; ni < 4; ++ni)
          acc[mi][ni] = __builtin_amdgcn_mfma_f32_16x16x32_fp8_fp8(
              a2, hi64(bfr[ni]), acc[mi][ni], 0, 0, 0);
      }
      __builtin_amdgcn_s_setprio(0);
      // counted drains (audited): A-phase needs t.kh1; B-phase needs (t+1).kh0
      if (kh == 0) {
        if (t < GNT - 1) asm volatile("s_waitcnt vmcnt(8)" ::: "memory");
        else             asm volatile("s_waitcnt vmcnt(0)" ::: "memory");
      } else {
        if (t < GNT - 2)      asm volatile("s_waitcnt vmcnt(8)" ::: "memory");
        else if (t == GNT - 2) asm volatile("s_waitcnt vmcnt(4)" ::: "memory");
      }
      __builtin_amdgcn_s_barrier();
    }
  }

  // epilogue: bias + fp8 NT store (pre-activation)
  #pragma unroll
  for (int ni = 0; ni < 4; ++ni) {
    const int col = tn + wc * 64 + ni * 16 + l15;
    const float bb = b1[col];
    #pragma unroll
    for (int mi = 0; mi < 8; ++mi)
      #pragma unroll
      for (int reg = 0; reg < 4; ++reg) {
        const int row = tm + wr * 128 + mi * 16 + hi * 4 + reg;
        __builtin_nontemporal_store(f2fp8(acc[mi][ni][reg] + bb),
                                    H + (size_t)row * NH + col);
      }
  }
}

// ---------------- self-pred gather: branch-free unrolled, fp8 T + fp8 H ----------------
template <int KM>
__device__ __forceinline__ void gather_chunk(
    const unsigned char* __restrict__ T, const int* idxrow,
    int oo, int bbv, float v[8]) {
  #pragma unroll
  for (int kc = 0; kc < KM; ++kc) {
    int c = idxrow[kc];
    float m = (c >= 0 && kc <= bbv) ? 1.f : 0.f;
    int cc = c < 0 ? 0 : (c >= CS ? CS - 1 : c);
    int2 tv = *(const int2*)(T + (size_t)(kc * CS + cc) * LSR + oo);  // 8 fp8
    float f[8];
    f[0] = __builtin_amdgcn_cvt_f32_fp8(tv.x, 0);
    f[1] = __builtin_amdgcn_cvt_f32_fp8(tv.x, 1);
    f[2] = __builtin_amdgcn_cvt_f32_fp8(tv.x, 2);
    f[3] = __builtin_amdgcn_cvt_f32_fp8(tv.x, 3);
    f[4] = __builtin_amdgcn_cvt_f32_fp8(tv.y, 0);
    f[5] = __builtin_amdgcn_cvt_f32_fp8(tv.y, 1);
    f[6] = __builtin_amdgcn_cvt_f32_fp8(tv.y, 2);
    f[7] = __builtin_amdgcn_cvt_f32_fp8(tv.y, 3);
    #pragma unroll
    for (int e = 0; e < 8; ++e) v[e] = fmaf(m, f[e], v[e]);
  }
}

// grid = dim3(3, SA_NBLK): x = 2048-col stripe, y = 32-row block.
// H is fp8 in-place: read pre-act fp8, add self_pred, relu, store fp8 + stats.
__global__ __launch_bounds__(256) void k_selfadd(
    unsigned char* __restrict__ H,         // [NROW][NH] fp8, in-place
    const unsigned char* __restrict__ T,   // [LSC][LSR] fp8 (linear_self^T)
    const int* __restrict__ ci,
    float* __restrict__ partials) {        // [2][SA_NBLK][NH]
  __shared__ int idxs[SA_ROWS][NCB];
  const int tid = threadIdx.x;
  const int row0 = blockIdx.y * SA_ROWS;
  const int sx = blockIdx.x;               // 0..2, block-uniform
  for (int i = tid; i < SA_ROWS * NCB; i += 256)
    idxs[i >> 4][i & 15] = ci[(size_t)(row0 + (i >> 4)) * NCB + (i & 15)];
  __syncthreads();

  const int col0 = sx * 2048 + tid * 8;
  const int o = col0 - HD;
  const int oo = o < 0 ? 0 : o;
  const int bb = o < 0 ? -1 : o / HD;

  float cs[8] = {0}, cq[8] = {0};

  for (int rr = 0; rr < SA_ROWS; ++rr) {
    const size_t ro = (size_t)(row0 + rr) * NH;
    int2v hv = __builtin_nontemporal_load((const int2v*)(H + ro + col0));
    float v[8];
    v[0] = __builtin_amdgcn_cvt_f32_fp8(hv[0], 0);
    v[1] = __builtin_amdgcn_cvt_f32_fp8(hv[0], 1);
    v[2] = __builtin_amdgcn_cvt_f32_fp8(hv[0], 2);
    v[3] = __builtin_amdgcn_cvt_f32_fp8(hv[0], 3);
    v[4] = __builtin_amdgcn_cvt_f32_fp8(hv[1], 0);
    v[5] = __builtin_amdgcn_cvt_f32_fp8(hv[1], 1);
    v[6] = __builtin_amdgcn_cvt_f32_fp8(hv[1], 2);
    v[7] = __builtin_amdgcn_cvt_f32_fp8(hv[1], 3);
    switch (sx) {  // block-uniform branch, compile-time gather depth
      case 0: gather_chunk<5>(T, idxs[rr], oo, bb, v); break;
      case 1: gather_chunk<10>(T, idxs[rr], oo, bb, v); break;
      default: gather_chunk<15>(T, idxs[rr], oo, bb, v); break;
    }
    float x[8];
    #pragma unroll
    for (int e = 0; e < 8; ++e) x[e] = fmaxf(v[e], 0.f);
    int2v ov;
    unsigned w0 = __builtin_amdgcn_cvt_pk_fp8_f32(x[0], x[1], 0, false);
    w0 = __builtin_amdgcn_cvt_pk_fp8_f32(x[2], x[3], w0, true);
    unsigned w1 = __builtin_amdgcn_cvt_pk_fp8_f32(x[4], x[5], 0, false);
    w1 = __builtin_amdgcn_cvt_pk_fp8_f32(x[6], x[7], w1, true);
    ov[0] = (int)w0; ov[1] = (int)w1;
    // stats from the fp8-rounded stored value (literal selectors)
    float xr0 = __builtin_amdgcn_cvt_f32_fp8(w0, 0);
    float xr1 = __builtin_amdgcn_cvt_f32_fp8(w0, 1);
    float xr2 = __builtin_amdgcn_cvt_f32_fp8(w0, 2);
    float xr3 = __builtin_amdgcn_cvt_f32_fp8(w0, 3);
    float xr4 = __builtin_amdgcn_cvt_f32_fp8(w1, 0);
    float xr5 = __builtin_amdgcn_cvt_f32_fp8(w1, 1);
    float xr6 = __builtin_amdgcn_cvt_f32_fp8(w1, 2);
    float xr7 = __builtin_amdgcn_cvt_f32_fp8(w1, 3);
    cs[0] += xr0; cq[0] += xr0 * xr0;
    cs[1] += xr1; cq[1] += xr1 * xr1;
    cs[2] += xr2; cq[2] += xr2 * xr2;
    cs[3] += xr3; cq[3] += xr3 * xr3;
    cs[4] += xr4; cq[4] += xr4 * xr4;
    cs[5] += xr5; cq[5] += xr5 * xr5;
    cs[6] += xr6; cq[6] += xr6 * xr6;
    cs[7] += xr7; cq[7] += xr7 * xr7;
    __builtin_nontemporal_store(ov, (int2v*)(H + ro + col0));
  }

  float* Ps = partials + (size_t)blockIdx.y * NH + col0;
  float* Pq = partials + (size_t)(SA_NBLK + blockIdx.y) * NH + col0;
  float4 a = {cs[0], cs[1], cs[2], cs[3]};
  float4 b4 = {cs[4], cs[5], cs[6], cs[7]};
  *(float4*)Ps = a; *(float4*)(Ps + 4) = b4;
  float4 c4 = {cq[0], cq[1], cq[2], cq[3]};
  float4 d4 = {cq[4], cq[5], cq[6], cq[7]};
  *(float4*)Pq = c4; *(float4*)(Pq + 4) = d4;
}

// ---------------- reduce partials -> colsum/colsq ----------------
// grid dim3(NH/256, 8)
__global__ void k_red(const float* __restrict__ partials,
                      float* __restrict__ colsum, float* __restrict__ colsq) {
  int j = blockIdx.x * 256 + threadIdx.x;
  const float* Ps = partials;
  const float* Pq = partials + (size_t)SA_NBLK * NH;
  float s = 0.f, q = 0.f;
  const int b0 = blockIdx.y * (SA_NBLK / 8), b1 = b0 + SA_NBLK / 8;
  for (int by = b0; by < b1; ++by) {
    s += Ps[(size_t)by * NH + j];
    q += Pq[(size_t)by * NH + j];
  }
  atomicAdd(colsum + j, s);
  atomicAdd(colsq + j, q);
}

// ---------------- BN params ----------------
__global__ void k_bn(const float* __restrict__ colsum, const float* __restrict__ colsq,
                     const float* __restrict__ gamma, const float* __restrict__ beta,
                     float* __restrict__ scale, float* __restrict__ shift) {
  int j = blockIdx.x * 256 + threadIdx.x;
  if (j >= NH) return;
  float mean = colsum[j] * (1.f / NROW);
  float var = colsq[j] * (1.f / NROW) - mean * mean;
  var = fmaxf(var, 0.f);
  float rs = rsqrtf(var + 1e-5f);
  float g = gamma[j] * rs;
  scale[j] = g;
  shift[j] = beta[j] - mean * g;
}

// ---------------- fold BN into linear2/bias2 (fp8 L2b) ----------------
__global__ __launch_bounds__(128) void k_fold(
    const float* __restrict__ L2, const float* __restrict__ bias2,
    const float* __restrict__ scale, const float* __restrict__ shift,
    unsigned char* __restrict__ L2b8, float* __restrict__ bias2p) {
  __shared__ float red[2];
  int kc = blockIdx.x;        // k*256 + c
  int k = kc >> 8;
  size_t off = (size_t)kc * HD;
  float a = 0.f;
  for (int h = threadIdx.x; h < HD; h += 128) {
    float wv = L2[off + h];
    int jh = k * HD + h;
    L2b8[off + h] = f2fp8(wv * scale[jh]);
    a += wv * shift[jh];
  }
  #pragma unroll
  for (int m = 1; m < 64; m <<= 1) a += __shfl_xor(a, m);
  if ((threadIdx.x & 63) == 0) red[threadIdx.x >> 6] = a;
  __syncthreads();
  if (threadIdx.x == 0) bias2p[kc] = bias2[kc] + red[0] + red[1];
}

// ---------------- pass C (fp8): logits GEMM + log-softmax + target gather ----------------
// grid dim3(256,16); XCD swizzle (2 codebooks/XCD). 6 phases of K=64; K-half
// loop hoisted (independent MFMA sweeps); 3-region counted vmcnt(5).
__global__ __launch_bounds__(256, 2) void k_passc(
    const unsigned char* __restrict__ H,      // [NROW][NH] fp8
    const unsigned char* __restrict__ L2b8,   // [NCB][CS][HD] fp8 (BN-folded)
    const float* __restrict__ bias2p,         // [NCB][CS]
    const int* __restrict__ ci,
    float* __restrict__ out) {
  __shared__ char smem[64 * 260 * 4];  // 66560B; 3x20480 staging aliased under lg
  __shared__ float red[4];
  float* lg = (float*)smem;            // [64][260]

  const int tid = threadIdx.x, lane = tid & 63, w = tid >> 6;
  const int bidf = blockIdx.y * gridDim.x + blockIdx.x;  // 0..4095
  const int xcd = bidf & 7, p = bidf >> 3;               // p in [0,512)
  const int k = xcd * 2 + (p & 1);
  const int tm = (p >> 1) * 64;
  const int r = lane & 15, hi = lane >> 4;
  const int w64 = tid & ~63;

  auto Asb = [&](int r3) { return (int4v*)(smem + r3 * 20480); };           // 4KB: [64 rows][4 granules]
  auto Bsb = [&](int r3) { return (int4v*)(smem + r3 * 20480 + 4096); };    // 16KB: [256 rows][4 granules]

  auto STAGE = [&](int r3, int kk) {
    const int kb = kk * 64;     // fp8 bytes along K
    {
      const int row = tid >> 2;
      const int pc = (tid & 3) ^ ((row >> 1) & 3);
      gload16(Asb(r3) + w64, H + (size_t)(tm + row) * NH + k * HD + kb + pc * 16);
    }
    #pragma unroll
    for (int i = 0; i < 4; ++i) {
      const int slot = i * 256 + tid;
      const int row = slot >> 2;
      const int pc = (slot & 3) ^ ((row >> 1) & 3);
      gload16(Bsb(r3) + i * 256 + w64,
              L2b8 + (size_t)(k * CS + row) * HD + kb + pc * 16);
    }
  };

  f32x4 acc[4][4] = {};
  STAGE(0, 0);
  STAGE(1, 1);
  asm volatile("s_waitcnt vmcnt(5)" ::: "memory");   // region 0 landed
  __builtin_amdgcn_s_barrier();

  for (int kk = 0; kk < HD / 64; ++kk) {  // 6 phases
    const int r3 = kk % 3;
    int4v af[4], bfr[4];
    #pragma unroll
    for (int mi = 0; mi < 4; ++mi) {
      const int row = mi * 16 + r;
      af[mi] = Asb(r3)[row * 4 + (hi ^ ((row >> 1) & 3))];
    }
    #pragma unroll
    for (int ni = 0; ni < 4; ++ni) {
      const int row = w * 64 + ni * 16 + r;
      bfr[ni] = Bsb(r3)[row * 4 + (hi ^ ((row >> 1) & 3))];
    }
    if (kk + 2 < HD / 64) STAGE((kk + 2) % 3, kk + 2);
    __builtin_amdgcn_s_setprio(1);
    // K-half 0 sweep (16 independent MFMAs)
    #pragma unroll
    for (int mi = 0; mi < 4; ++mi) {
      const long a1 = lo64(af[mi]);
      #pragma unroll
      for (int ni = 0; ni < 4; ++ni)
        acc[mi][ni] = __builtin_amdgcn_mfma_f32_16x16x32_fp8_fp8(
            a1, lo64(bfr[ni]), acc[mi][ni], 0, 0, 0);
    }
    // K-half 1 sweep
    #pragma unroll
    for (int mi = 0; mi < 4; ++mi) {
      const long a2 = hi64(af[mi]);
      #pragma unroll
      for (int ni = 0; ni < 4; ++ni)
        acc[mi][ni] = __builtin_amdgcn_mfma_f32_16x16x32_fp8_fp8(
            a2, hi64(bfr[ni]), acc[mi][ni], 0, 0, 0);
    }
    __builtin_amdgcn_s_setprio(0);
    if (kk + 1 < HD / 64) {
      if (kk + 2 < HD / 64) asm volatile("s_waitcnt vmcnt(5)" ::: "memory");
      else                  asm volatile("s_waitcnt vmcnt(0)" ::: "memory");
    }
    __builtin_amdgcn_s_barrier();
  }

  const int lr0 = hi * 4;
  #pragma unroll
  for (int mi = 0; mi < 4; ++mi)
    #pragma unroll
    for (int ni = 0; ni < 4; ++ni) {
      int col = w * 64 + ni * 16 + r;
      float bb = bias2p[k * CS + col];
      #pragma unroll
      for (int reg = 0; reg < 4; ++reg) {
        int row = mi * 16 + lr0 + reg;
        lg[row * 260 + col] = acc[mi][ni][reg] + bb;
      }
    }
  __syncthreads();

  int row = tid >> 2, part = tid & 3;
  const float4* rp = (const float4*)(lg + row * 260 + part * 64);
  float s = 0.f;
  #pragma unroll
  for (int i = 0; i < 16; ++i) {
    float4 v = rp[i];
    s += __expf(v.x) + __expf(v.y) + __expf(v.z) + __expf(v.w);
  }
  s += __shfl_xor(s, 1);
  s += __shfl_xor(s, 2);
  float contrib = 0.f;
  if (part == 0) {
    float lse = __logf(s);
    int c = ci[(size_t)(tm + row) * NCB + k];
    if (c >= 0) {
      c = c < CS ? c : CS - 1;
      contrib = lg[row * 260 + c] - lse;
    }
  }
  #pragma unroll
  for (int msk = 1; msk < 64; msk <<= 1) contrib += __shfl_xor(contrib, msk);
  if (lane == 0) red[w] = contrib;
  __syncthreads();
  if (tid == 0) atomicAdd(out, red[0] + red[1] + red[2] + red[3]);
}

extern "C" void kernel_launch(void* const* d_in, const int* in_sizes, int n_in,
                              void* d_out, int out_size, void* d_ws, size_t ws_size,
                              hipStream_t stream) {
  const float* predictor = (const float*)d_in[0];
  const int* cbidx       = (const int*)d_in[1];
  const float* W1        = (const float*)d_in[2];
  const float* b1        = (const float*)d_in[3];
  const float* lself     = (const float*)d_in[4];
  const float* gamma     = (const float*)d_in[5];
  const float* beta      = (const float*)d_in[6];
  const float* L2        = (const float*)d_in[7];
  const float* bias2     = (const float*)d_in[8];
  float* out = (float*)d_out;

  char* ws = (char*)d_ws;
  size_t off = 0;
  auto alloc = [&](size_t bytes) {
    char* p = ws + off;
    off += (bytes + 255) & ~(size_t)255;
    return p;
  };
  unsigned char* predB8  = (unsigned char*)alloc((size_t)NROW * PD);
  unsigned char* W1B8    = (unsigned char*)alloc((size_t)NH * PD);
  unsigned char* T       = (unsigned char*)alloc((size_t)LSC * LSR);
  unsigned char* H8      = (unsigned char*)alloc((size_t)NROW * NH);
  unsigned char* L2b8    = (unsigned char*)alloc((size_t)NCB * CS * HD);
  float* partials = (float*)alloc((size_t)2 * SA_NBLK * NH * 4);
  float* colsum = (float*)alloc(NH * 4);
  float* colsq  = (float*)alloc(NH * 4);
  float* scale  = (float*)alloc(NH * 4);
  float* shift  = (float*)alloc(NH * 4);
  float* bias2p = (float*)alloc(NCB * CS * 4);

  hipMemsetAsync(d_out, 0, 2 * sizeof(float), stream);
  hipMemsetAsync(colsum, 0, NH * 4, stream);
  hipMemsetAsync(colsq, 0, NH * 4, stream);

  k_f2b8<<<2048, 256, 0, stream>>>(predictor, (unsigned*)predB8, NROW * PD / 8);
  k_f2b8<<<2048, 256, 0, stream>>>(W1, (unsigned*)W1B8, NH * PD / 8);
  k_transpose<<<dim3(LSC / 32, LSR / 32), 256, 0, stream>>>(lself, T);
  k_count<<<NROW / 256, 256, 0, stream>>>(cbidx, out);
  k_gemm1<<<(NROW / 256) * (NH / 256), 512, 0, stream>>>(predB8, W1B8, b1, H8);
  k_selfadd<<<dim3(3, SA_NBLK), 256, 0, stream>>>(H8, T, cbidx, partials);
  k_red<<<dim3(NH / 256, 8), 256, 0, stream>>>(partials, colsum, colsq);
  k_bn<<<NH / 256, 256, 0, stream>>>(colsum, colsq, gamma, beta, scale, shift);
  k_fold<<<NCB * CS, 128, 0, stream>>>(L2, bias2, scale, shift, L2b8, bias2p);
  k_passc<<<dim3(NROW / 64, NCB), 256, 0, stream>>>(H8, L2b8, bias2p, cbidx, out);
}

// Round 19
// 697.536 us; speedup vs baseline: 1.6541x; 1.0491x over previous
//
#include <hip/hip_runtime.h>
#include <hip/hip_bf16.h>

#define NCB 16
#define CS 256
#define HD 384
#define PD 2048
#define NROW 16384
#define NH 6144      // NCB*HD
#define LSR 5760     // (NCB-1)*HD  rows of linear_self
#define LSC 3840     // (NCB-1)*CS  cols of linear_self
#define SA_ROWS 32
#define SA_NBLK (NROW / SA_ROWS)   // 512
#define GK 32                      // 32 K-steps of 64 bytes for fp8 gemm1

typedef __bf16 bf16x8 __attribute__((ext_vector_type(8)));
typedef float f32x4 __attribute__((ext_vector_type(4)));
typedef int int4v __attribute__((ext_vector_type(4)));
typedef int int2v __attribute__((ext_vector_type(2)));

__device__ __forceinline__ unsigned short f2bf(float f) {
  unsigned u = __builtin_bit_cast(unsigned, f);
  u = (u + 0x7fffu + ((u >> 16) & 1u)) >> 16;
  return (unsigned short)u;
}
__device__ __forceinline__ float bf2f(unsigned short h) {
  unsigned u = ((unsigned)h) << 16;
  return __builtin_bit_cast(float, u);
}
__device__ __forceinline__ unsigned char f2fp8(float f) {
  return (unsigned char)__builtin_amdgcn_cvt_pk_fp8_f32(f, f, 0, false);
}
__device__ __forceinline__ long lo64(int4v v) {
  int2v t; t[0] = v[0]; t[1] = v[1];
  return __builtin_bit_cast(long, t);
}
__device__ __forceinline__ long hi64(int4v v) {
  int2v t; t[0] = v[2]; t[1] = v[3];
  return __builtin_bit_cast(long, t);
}

__device__ __forceinline__ void gload16(void* lds, const void* g) {
  __builtin_amdgcn_global_load_lds(
      (const __attribute__((address_space(1))) unsigned int*)g,
      (__attribute__((address_space(3))) unsigned int*)lds, 16, 0, 0);
}

// ---------------- fp32 -> fp8 e4m3 conversion (8 elements/thread/iter) ----------------
__global__ void k_f2b8(const float* __restrict__ in, unsigned* __restrict__ out, int n8) {
  for (int i = blockIdx.x * 256 + threadIdx.x; i < n8; i += gridDim.x * 256) {
    float4 a = ((const float4*)in)[i * 2];
    float4 b = ((const float4*)in)[i * 2 + 1];
    unsigned lo = __builtin_amdgcn_cvt_pk_fp8_f32(a.x, a.y, 0, false);
    lo = __builtin_amdgcn_cvt_pk_fp8_f32(a.z, a.w, lo, true);
    unsigned hi = __builtin_amdgcn_cvt_pk_fp8_f32(b.x, b.y, 0, false);
    hi = __builtin_amdgcn_cvt_pk_fp8_f32(b.z, b.w, hi, true);
    uint2 o = {lo, hi};
    ((uint2*)out)[i] = o;
  }
}

// ---------------- transpose linear_self (5760x3840 f32) -> T (3840x5760 fp8 e4m3) ----------------
__global__ __launch_bounds__(256) void k_transpose(const float* __restrict__ LS,
                                                   unsigned char* __restrict__ T) {
  __shared__ float tile[32][33];
  int tx = threadIdx.x & 31, ty = threadIdx.x >> 5;
  int c0 = blockIdx.x * 32;  // col of LS = row of T
  int r0 = blockIdx.y * 32;  // row of LS = col of T
  for (int i = ty; i < 32; i += 8)
    tile[i][tx] = LS[(size_t)(r0 + i) * LSC + c0 + tx];
  __syncthreads();
  const int i = threadIdx.x >> 3;        // T-row offset 0..31
  const int q = (threadIdx.x & 7) * 4;   // r-offset 0,4,..,28
  unsigned u = __builtin_amdgcn_cvt_pk_fp8_f32(tile[q][i], tile[q + 1][i], 0, false);
  u = __builtin_amdgcn_cvt_pk_fp8_f32(tile[q + 2][i], tile[q + 3][i], u, true);
  *(unsigned*)(T + (size_t)(c0 + i) * LSR + r0 + q) = u;
}

// ---------------- count valid[:,0] ----------------
__global__ void k_count(const int* __restrict__ ci, float* __restrict__ out) {
  int n = blockIdx.x * 256 + threadIdx.x;
  float v = (n < NROW && ci[(size_t)n * NCB] >= 0) ? 1.f : 0.f;
  #pragma unroll
  for (int m = 1; m < 64; m <<= 1) v += __shfl_xor(v, m);
  if ((threadIdx.x & 63) == 0) atomicAdd(out + 1, v);
}

// ---------------- GEMM1 (fp8): 256x128 tile, BK=64, dbuf 48KB, 2 blocks/CU ----------------
// Small-tile variant: acc[4][4] (64 AGPR) keeps total regs <=128 so TWO blocks
// co-reside per CU — one block's frag-read/stage phase hides under the other's
// MFMA phase (the overlap the 256x256/1-block kernel couldn't have).
// Stage-1-ahead dbuf, vmcnt(0)+barrier per window; barrier#1 removed (r11 audit).
__global__ __launch_bounds__(512, 4) void k_gemm1(
    const unsigned char* __restrict__ A,   // predictor fp8 [NROW][PD]
    const unsigned char* __restrict__ B,   // W1 fp8 [NH][PD]
    const float* __restrict__ b1,
    unsigned char* __restrict__ H) {       // out [NROW][NH] fp8 (pre-activation)
  __shared__ int4v Al[2][1024];   // [buf][row(256)*4 + pc]  16KB/buf
  __shared__ int4v Bl[2][512];    // [buf][row(128)*4 + pc]   8KB/buf

  const int tid = threadIdx.x;
  const int lane = tid & 63;
  const int w = tid >> 6;             // 0..7
  const int wr = w >> 1, wc = w & 1;  // wave grid 4(M) x 2(N), wave = 64x64
  const int l15 = lane & 15, hi = lane >> 4;
  const int w64 = tid & ~63;

  // XCD swizzle: grid 3072 = 64 mt x 48 nt; each XCD owns 6 nt (1.5MB B -> L2)
  const int bid = blockIdx.x;
  const int xcd = bid & 7, p = bid >> 3;   // p in [0,384)
  const int nt = xcd * 6 + p % 6;
  const int mt = p / 6;
  const int tm = mt * 256, tn = nt * 128;

  f32x4 acc[4][4] = {};

  auto STAGE = [&](int buf, int t) {
    const int kb = t * 64;   // byte offset along K
    #pragma unroll
    for (int g = 0; g < 2; ++g) {   // A: 1024 granules
      const int slot = g * 512 + tid;
      const int row = slot >> 2;
      const int lc = (slot & 3) ^ ((row >> 1) & 3);
      gload16(&Al[buf][g * 512 + w64], A + (size_t)(tm + row) * PD + kb + lc * 16);
    }
    {                                // B: 512 granules
      const int row = tid >> 2;
      const int lc = (tid & 3) ^ ((row >> 1) & 3);
      gload16(&Bl[buf][w64], B + (size_t)(tn + row) * PD + kb + lc * 16);
    }
  };

  STAGE(0, 0);
  asm volatile("s_waitcnt vmcnt(0)" ::: "memory");
  __builtin_amdgcn_s_barrier();

  for (int t = 0; t < GK; ++t) {
    const int buf = t & 1;
    // frag reads (swizzled, b128 = K=64 fp8)
    int4v af[4], bfr[4];
    #pragma unroll
    for (int mi = 0; mi < 4; ++mi) {
      const int row = wr * 64 + mi * 16 + l15;
      af[mi] = Al[buf][row * 4 + (hi ^ ((row >> 1) & 3))];
    }
    #pragma unroll
    for (int ni = 0; ni < 4; ++ni) {
      const int row = wc * 64 + ni * 16 + l15;
      bfr[ni] = Bl[buf][row * 4 + (hi ^ ((row >> 1) & 3))];
    }
    if (t + 1 < GK) STAGE(buf ^ 1, t + 1);   // next-window loads in flight
    // (no barrier here — cross-wave/cross-block read-vs-MFMA overlap)
    __builtin_amdgcn_s_setprio(1);
    #pragma unroll
    for (int mi = 0; mi < 4; ++mi) {
      const long a1 = lo64(af[mi]);
      #pragma unroll
      for (int ni = 0; ni < 4; ++ni)
        acc[mi][ni] = __builtin_amdgcn_mfma_f32_16x16x32_fp8_fp8(
            a1, lo64(bfr[ni]), acc[mi][ni], 0, 0, 0);
    }
    #pragma unroll
    for (int mi = 0; mi < 4; ++mi) {
      const long a2 = hi64(af[mi]);
      #pragma unroll
      for (int ni = 0; ni < 4; ++ni)
        acc[mi][ni] = __builtin_amdgcn_mfma_f32_16x16x32_fp8_fp8(
            a2, hi64(bfr[ni]), acc[mi][ni], 0, 0, 0);
    }
    __builtin_amdgcn_s_setprio(0);
    if (t + 1 < GK) {
      asm volatile("s_waitcnt vmcnt(0)" ::: "memory");
      __builtin_amdgcn_s_barrier();
    }
  }

  // epilogue: bias + fp8 NT store (pre-activation)
  #pragma unroll
  for (int ni = 0; ni < 4; ++ni) {
    const int col = tn + wc * 64 + ni * 16 + l15;
    const float bb = b1[col];
    #pragma unroll
    for (int mi = 0; mi < 4; ++mi)
      #pragma unroll
      for (int reg = 0; reg < 4; ++reg) {
        const int row = tm + wr * 64 + mi * 16 + hi * 4 + reg;
        __builtin_nontemporal_store(f2fp8(acc[mi][ni][reg] + bb),
                                    H + (size_t)row * NH + col);
      }
  }
}

// ---------------- self-pred gather: branch-free unrolled, fp8 T + fp8 H ----------------
template <int KM>
__device__ __forceinline__ void gather_chunk(
    const unsigned char* __restrict__ T, const int* idxrow,
    int oo, int bbv, float v[8]) {
  #pragma unroll
  for (int kc = 0; kc < KM; ++kc) {
    int c = idxrow[kc];
    float m = (c >= 0 && kc <= bbv) ? 1.f : 0.f;
    int cc = c < 0 ? 0 : (c >= CS ? CS - 1 : c);
    int2 tv = *(const int2*)(T + (size_t)(kc * CS + cc) * LSR + oo);  // 8 fp8
    float f[8];
    f[0] = __builtin_amdgcn_cvt_f32_fp8(tv.x, 0);
    f[1] = __builtin_amdgcn_cvt_f32_fp8(tv.x, 1);
    f[2] = __builtin_amdgcn_cvt_f32_fp8(tv.x, 2);
    f[3] = __builtin_amdgcn_cvt_f32_fp8(tv.x, 3);
    f[4] = __builtin_amdgcn_cvt_f32_fp8(tv.y, 0);
    f[5] = __builtin_amdgcn_cvt_f32_fp8(tv.y, 1);
    f[6] = __builtin_amdgcn_cvt_f32_fp8(tv.y, 2);
    f[7] = __builtin_amdgcn_cvt_f32_fp8(tv.y, 3);
    #pragma unroll
    for (int e = 0; e < 8; ++e) v[e] = fmaf(m, f[e], v[e]);
  }
}

// grid = dim3(3, SA_NBLK): x = 2048-col stripe, y = 32-row block.
__global__ __launch_bounds__(256) void k_selfadd(
    unsigned char* __restrict__ H,         // [NROW][NH] fp8, in-place
    const unsigned char* __restrict__ T,   // [LSC][LSR] fp8 (linear_self^T)
    const int* __restrict__ ci,
    float* __restrict__ partials) {        // [2][SA_NBLK][NH]
  __shared__ int idxs[SA_ROWS][NCB];
  const int tid = threadIdx.x;
  const int row0 = blockIdx.y * SA_ROWS;
  const int sx = blockIdx.x;               // 0..2, block-uniform
  for (int i = tid; i < SA_ROWS * NCB; i += 256)
    idxs[i >> 4][i & 15] = ci[(size_t)(row0 + (i >> 4)) * NCB + (i & 15)];
  __syncthreads();

  const int col0 = sx * 2048 + tid * 8;
  const int o = col0 - HD;
  const int oo = o < 0 ? 0 : o;
  const int bb = o < 0 ? -1 : o / HD;

  float cs[8] = {0}, cq[8] = {0};

  for (int rr = 0; rr < SA_ROWS; ++rr) {
    const size_t ro = (size_t)(row0 + rr) * NH;
    int2v hv = __builtin_nontemporal_load((const int2v*)(H + ro + col0));
    float v[8];
    v[0] = __builtin_amdgcn_cvt_f32_fp8(hv[0], 0);
    v[1] = __builtin_amdgcn_cvt_f32_fp8(hv[0], 1);
    v[2] = __builtin_amdgcn_cvt_f32_fp8(hv[0], 2);
    v[3] = __builtin_amdgcn_cvt_f32_fp8(hv[0], 3);
    v[4] = __builtin_amdgcn_cvt_f32_fp8(hv[1], 0);
    v[5] = __builtin_amdgcn_cvt_f32_fp8(hv[1], 1);
    v[6] = __builtin_amdgcn_cvt_f32_fp8(hv[1], 2);
    v[7] = __builtin_amdgcn_cvt_f32_fp8(hv[1], 3);
    switch (sx) {
      case 0: gather_chunk<5>(T, idxs[rr], oo, bb, v); break;
      case 1: gather_chunk<10>(T, idxs[rr], oo, bb, v); break;
      default: gather_chunk<15>(T, idxs[rr], oo, bb, v); break;
    }
    float x[8];
    #pragma unroll
    for (int e = 0; e < 8; ++e) x[e] = fmaxf(v[e], 0.f);
    int2v ov;
    unsigned w0 = __builtin_amdgcn_cvt_pk_fp8_f32(x[0], x[1], 0, false);
    w0 = __builtin_amdgcn_cvt_pk_fp8_f32(x[2], x[3], w0, true);
    unsigned w1 = __builtin_amdgcn_cvt_pk_fp8_f32(x[4], x[5], 0, false);
    w1 = __builtin_amdgcn_cvt_pk_fp8_f32(x[6], x[7], w1, true);
    ov[0] = (int)w0; ov[1] = (int)w1;
    float xr0 = __builtin_amdgcn_cvt_f32_fp8(w0, 0);
    float xr1 = __builtin_amdgcn_cvt_f32_fp8(w0, 1);
    float xr2 = __builtin_amdgcn_cvt_f32_fp8(w0, 2);
    float xr3 = __builtin_amdgcn_cvt_f32_fp8(w0, 3);
    float xr4 = __builtin_amdgcn_cvt_f32_fp8(w1, 0);
    float xr5 = __builtin_amdgcn_cvt_f32_fp8(w1, 1);
    float xr6 = __builtin_amdgcn_cvt_f32_fp8(w1, 2);
    float xr7 = __builtin_amdgcn_cvt_f32_fp8(w1, 3);
    cs[0] += xr0; cq[0] += xr0 * xr0;
    cs[1] += xr1; cq[1] += xr1 * xr1;
    cs[2] += xr2; cq[2] += xr2 * xr2;
    cs[3] += xr3; cq[3] += xr3 * xr3;
    cs[4] += xr4; cq[4] += xr4 * xr4;
    cs[5] += xr5; cq[5] += xr5 * xr5;
    cs[6] += xr6; cq[6] += xr6 * xr6;
    cs[7] += xr7; cq[7] += xr7 * xr7;
    __builtin_nontemporal_store(ov, (int2v*)(H + ro + col0));
  }

  float* Ps = partials + (size_t)blockIdx.y * NH + col0;
  float* Pq = partials + (size_t)(SA_NBLK + blockIdx.y) * NH + col0;
  float4 a = {cs[0], cs[1], cs[2], cs[3]};
  float4 b4 = {cs[4], cs[5], cs[6], cs[7]};
  *(float4*)Ps = a; *(float4*)(Ps + 4) = b4;
  float4 c4 = {cq[0], cq[1], cq[2], cq[3]};
  float4 d4 = {cq[4], cq[5], cq[6], cq[7]};
  *(float4*)Pq = c4; *(float4*)(Pq + 4) = d4;
}

// ---------------- reduce partials -> colsum/colsq ----------------
__global__ void k_red(const float* __restrict__ partials,
                      float* __restrict__ colsum, float* __restrict__ colsq) {
  int j = blockIdx.x * 256 + threadIdx.x;
  const float* Ps = partials;
  const float* Pq = partials + (size_t)SA_NBLK * NH;
  float s = 0.f, q = 0.f;
  const int b0 = blockIdx.y * (SA_NBLK / 8), b1 = b0 + SA_NBLK / 8;
  for (int by = b0; by < b1; ++by) {
    s += Ps[(size_t)by * NH + j];
    q += Pq[(size_t)by * NH + j];
  }
  atomicAdd(colsum + j, s);
  atomicAdd(colsq + j, q);
}

// ---------------- BN params ----------------
__global__ void k_bn(const float* __restrict__ colsum, const float* __restrict__ colsq,
                     const float* __restrict__ gamma, const float* __restrict__ beta,
                     float* __restrict__ scale, float* __restrict__ shift) {
  int j = blockIdx.x * 256 + threadIdx.x;
  if (j >= NH) return;
  float mean = colsum[j] * (1.f / NROW);
  float var = colsq[j] * (1.f / NROW) - mean * mean;
  var = fmaxf(var, 0.f);
  float rs = rsqrtf(var + 1e-5f);
  float g = gamma[j] * rs;
  scale[j] = g;
  shift[j] = beta[j] - mean * g;
}

// ---------------- fold BN into linear2/bias2 (fp8 L2b) ----------------
__global__ __launch_bounds__(128) void k_fold(
    const float* __restrict__ L2, const float* __restrict__ bias2,
    const float* __restrict__ scale, const float* __restrict__ shift,
    unsigned char* __restrict__ L2b8, float* __restrict__ bias2p) {
  __shared__ float red[2];
  int kc = blockIdx.x;        // k*256 + c
  int k = kc >> 8;
  size_t off = (size_t)kc * HD;
  float a = 0.f;
  for (int h = threadIdx.x; h < HD; h += 128) {
    float wv = L2[off + h];
    int jh = k * HD + h;
    L2b8[off + h] = f2fp8(wv * scale[jh]);
    a += wv * shift[jh];
  }
  #pragma unroll
  for (int m = 1; m < 64; m <<= 1) a += __shfl_xor(a, m);
  if ((threadIdx.x & 63) == 0) red[threadIdx.x >> 6] = a;
  __syncthreads();
  if (threadIdx.x == 0) bias2p[kc] = bias2[kc] + red[0] + red[1];
}

// ---------------- pass C (fp8): logits GEMM + log-softmax + target gather ----------------
__global__ __launch_bounds__(256, 2) void k_passc(
    const unsigned char* __restrict__ H,      // [NROW][NH] fp8
    const unsigned char* __restrict__ L2b8,   // [NCB][CS][HD] fp8 (BN-folded)
    const float* __restrict__ bias2p,         // [NCB][CS]
    const int* __restrict__ ci,
    float* __restrict__ out) {
  __shared__ char smem[64 * 260 * 4];  // 66560B; 3x20480 staging aliased under lg
  __shared__ float red[4];
  float* lg = (float*)smem;            // [64][260]

  const int tid = threadIdx.x, lane = tid & 63, w = tid >> 6;
  const int bidf = blockIdx.y * gridDim.x + blockIdx.x;  // 0..4095
  const int xcd = bidf & 7, p = bidf >> 3;               // p in [0,512)
  const int k = xcd * 2 + (p & 1);
  const int tm = (p >> 1) * 64;
  const int r = lane & 15, hi = lane >> 4;
  const int w64 = tid & ~63;

  auto Asb = [&](int r3) { return (int4v*)(smem + r3 * 20480); };
  auto Bsb = [&](int r3) { return (int4v*)(smem + r3 * 20480 + 4096); };

  auto STAGE = [&](int r3, int kk) {
    const int kb = kk * 64;     // fp8 bytes along K
    {
      const int row = tid >> 2;
      const int pc = (tid & 3) ^ ((row >> 1) & 3);
      gload16(Asb(r3) + w64, H + (size_t)(tm + row) * NH + k * HD + kb + pc * 16);
    }
    #pragma unroll
    for (int i = 0; i < 4; ++i) {
      const int slot = i * 256 + tid;
      const int row = slot >> 2;
      const int pc = (slot & 3) ^ ((row >> 1) & 3);
      gload16(Bsb(r3) + i * 256 + w64,
              L2b8 + (size_t)(k * CS + row) * HD + kb + pc * 16);
    }
  };

  f32x4 acc[4][4] = {};
  STAGE(0, 0);
  STAGE(1, 1);
  asm volatile("s_waitcnt vmcnt(5)" ::: "memory");
  __builtin_amdgcn_s_barrier();

  for (int kk = 0; kk < HD / 64; ++kk) {  // 6 phases
    const int r3 = kk % 3;
    int4v af[4], bfr[4];
    #pragma unroll
    for (int mi = 0; mi < 4; ++mi) {
      const int row = mi * 16 + r;
      af[mi] = Asb(r3)[row * 4 + (hi ^ ((row >> 1) & 3))];
    }
    #pragma unroll
    for (int ni = 0; ni < 4; ++ni) {
      const int row = w * 64 + ni * 16 + r;
      bfr[ni] = Bsb(r3)[row * 4 + (hi ^ ((row >> 1) & 3))];
    }
    if (kk + 2 < HD / 64) STAGE((kk + 2) % 3, kk + 2);
    __builtin_amdgcn_s_setprio(1);
    #pragma unroll
    for (int mi = 0; mi < 4; ++mi) {
      const long a1 = lo64(af[mi]);
      #pragma unroll
      for (int ni = 0; ni < 4; ++ni)
        acc[mi][ni] = __builtin_amdgcn_mfma_f32_16x16x32_fp8_fp8(
            a1, lo64(bfr[ni]), acc[mi][ni], 0, 0, 0);
    }
    #pragma unroll
    for (int mi = 0; mi < 4; ++mi) {
      const long a2 = hi64(af[mi]);
      #pragma unroll
      for (int ni = 0; ni < 4; ++ni)
        acc[mi][ni] = __builtin_amdgcn_mfma_f32_16x16x32_fp8_fp8(
            a2, hi64(bfr[ni]), acc[mi][ni], 0, 0, 0);
    }
    __builtin_amdgcn_s_setprio(0);
    if (kk + 1 < HD / 64) {
      if (kk + 2 < HD / 64) asm volatile("s_waitcnt vmcnt(5)" ::: "memory");
      else                  asm volatile("s_waitcnt vmcnt(0)" ::: "memory");
    }
    __builtin_amdgcn_s_barrier();
  }

  const int lr0 = hi * 4;
  #pragma unroll
  for (int mi = 0; mi < 4; ++mi)
    #pragma unroll
    for (int ni = 0; ni < 4; ++ni) {
      int col = w * 64 + ni * 16 + r;
      float bb = bias2p[k * CS + col];
      #pragma unroll
      for (int reg = 0; reg < 4; ++reg) {
        int row = mi * 16 + lr0 + reg;
        lg[row * 260 + col] = acc[mi][ni][reg] + bb;
      }
    }
  __syncthreads();

  int row = tid >> 2, part = tid & 3;
  const float4* rp = (const float4*)(lg + row * 260 + part * 64);
  float s = 0.f;
  #pragma unroll
  for (int i = 0; i < 16; ++i) {
    float4 v = rp[i];
    s += __expf(v.x) + __expf(v.y) + __expf(v.z) + __expf(v.w);
  }
  s += __shfl_xor(s, 1);
  s += __shfl_xor(s, 2);
  float contrib = 0.f;
  if (part == 0) {
    float lse = __logf(s);
    int c = ci[(size_t)(tm + row) * NCB + k];
    if (c >= 0) {
      c = c < CS ? c : CS - 1;
      contrib = lg[row * 260 + c] - lse;
    }
  }
  #pragma unroll
  for (int msk = 1; msk < 64; msk <<= 1) contrib += __shfl_xor(contrib, msk);
  if (lane == 0) red[w] = contrib;
  __syncthreads();
  if (tid == 0) atomicAdd(out, red[0] + red[1] + red[2] + red[3]);
}

extern "C" void kernel_launch(void* const* d_in, const int* in_sizes, int n_in,
                              void* d_out, int out_size, void* d_ws, size_t ws_size,
                              hipStream_t stream) {
  const float* predictor = (const float*)d_in[0];
  const int* cbidx       = (const int*)d_in[1];
  const float* W1        = (const float*)d_in[2];
  const float* b1        = (const float*)d_in[3];
  const float* lself     = (const float*)d_in[4];
  const float* gamma     = (const float*)d_in[5];
  const float* beta      = (const float*)d_in[6];
  const float* L2        = (const float*)d_in[7];
  const float* bias2     = (const float*)d_in[8];
  float* out = (float*)d_out;

  char* ws = (char*)d_ws;
  size_t off = 0;
  auto alloc = [&](size_t bytes) {
    char* p = ws + off;
    off += (bytes + 255) & ~(size_t)255;
    return p;
  };
  unsigned char* predB8  = (unsigned char*)alloc((size_t)NROW * PD);
  unsigned char* W1B8    = (unsigned char*)alloc((size_t)NH * PD);
  unsigned char* T       = (unsigned char*)alloc((size_t)LSC * LSR);
  unsigned char* H8      = (unsigned char*)alloc((size_t)NROW * NH);
  unsigned char* L2b8    = (unsigned char*)alloc((size_t)NCB * CS * HD);
  float* partials = (float*)alloc((size_t)2 * SA_NBLK * NH * 4);
  float* colsum = (float*)alloc(NH * 4);
  float* colsq  = (float*)alloc(NH * 4);
  float* scale  = (float*)alloc(NH * 4);
  float* shift  = (float*)alloc(NH * 4);
  float* bias2p = (float*)alloc(NCB * CS * 4);

  hipMemsetAsync(d_out, 0, 2 * sizeof(float), stream);
  hipMemsetAsync(colsum, 0, NH * 4, stream);
  hipMemsetAsync(colsq, 0, NH * 4, stream);

  k_f2b8<<<2048, 256, 0, stream>>>(predictor, (unsigned*)predB8, NROW * PD / 8);
  k_f2b8<<<2048, 256, 0, stream>>>(W1, (unsigned*)W1B8, NH * PD / 8);
  k_transpose<<<dim3(LSC / 32, LSR / 32), 256, 0, stream>>>(lself, T);
  k_count<<<NROW / 256, 256, 0, stream>>>(cbidx, out);
  k_gemm1<<<(NROW / 256) * (NH / 128), 512, 0, stream>>>(predB8, W1B8, b1, H8);
  k_selfadd<<<dim3(3, SA_NBLK), 256, 0, stream>>>(H8, T, cbidx, partials);
  k_red<<<dim3(NH / 256, 8), 256, 0, stream>>>(partials, colsum, colsq);
  k_bn<<<NH / 256, 256, 0, stream>>>(colsum, colsq, gamma, beta, scale, shift);
  k_fold<<<NCB * CS, 128, 0, stream>>>(L2, bias2, scale, shift, L2b8, bias2p);
  k_passc<<<dim3(NROW / 64, NCB), 256, 0, stream>>>(H8, L2b8, bias2p, cbidx, out);
}